// Round 13
// baseline (376.450 us; speedup 1.0000x reference)
//
#include <hip/hip_runtime.h>
#include <hip/hip_bf16.h>
#include <cmath>

#define B_   2
#define L_   512
#define HID  2048
#define DH   128
#define NH   8
#define NHH  2
#define ROWS 1024  // B_*L_
#define NFUSE 6144 // 1024(q)+2048(k)+2048(v)+1024(g)

typedef float  f32x2  __attribute__((ext_vector_type(2)));
typedef float  f32x4  __attribute__((ext_vector_type(4)));
typedef __bf16 bf16x8 __attribute__((ext_vector_type(8)));

#define AS1(p) ((const __attribute__((address_space(1))) unsigned int*)(p))
#define AS3(p) ((__attribute__((address_space(3))) unsigned int*)(p))

__device__ __forceinline__ float dpp_xor1(float x) {
  int r = __builtin_amdgcn_update_dpp(0, __float_as_int(x), 0xB1, 0xF, 0xF, true);
  return __int_as_float(r);
}
__device__ __forceinline__ float dpp_xor2(float x) {
  int r = __builtin_amdgcn_update_dpp(0, __float_as_int(x), 0x4E, 0xF, 0xF, true);
  return __int_as_float(r);
}
__device__ __forceinline__ float dpp_hmirror(float x) {  // mirror within 8
  int r = __builtin_amdgcn_update_dpp(0, __float_as_int(x), 0x141, 0xF, 0xF, true);
  return __int_as_float(r);
}
__device__ __forceinline__ float dpp_rmirror(float x) {  // mirror within 16
  int r = __builtin_amdgcn_update_dpp(0, __float_as_int(x), 0x140, 0xF, 0xF, true);
  return __int_as_float(r);
}

// ---------------- f32 -> bf16 elementwise ----------------
__global__ void f2bf_kernel(const float* __restrict__ in, __hip_bfloat16* __restrict__ out, int n) {
  int i = blockIdx.x * 256 + threadIdx.x;
  if (i < n) out[i] = __float2bfloat16(in[i]);
}

// ---------------- 5 weight transposes in one dispatch (blockIdx.z selects) -------
__global__ __launch_bounds__(256) void transpose5_kernel(const float* __restrict__ Wq,
                                                         const float* __restrict__ Wk,
                                                         const float* __restrict__ Wv,
                                                         const float* __restrict__ Wg,
                                                         const float* __restrict__ Wo,
                                                         __hip_bfloat16* __restrict__ WT,
                                                         __hip_bfloat16* __restrict__ WoT) {
  const float* in; __hip_bfloat16* out; int K, N;
  switch (blockIdx.z) {
    case 0: in = Wq; out = WT;                          K = 2048; N = 1024; break;
    case 1: in = Wk; out = WT + (size_t)1024 * 2048;    K = 2048; N = 2048; break;
    case 2: in = Wv; out = WT + (size_t)3072 * 2048;    K = 2048; N = 2048; break;
    case 3: in = Wg; out = WT + (size_t)5120 * 2048;    K = 2048; N = 1024; break;
    default: in = Wo; out = WoT;                        K = 1024; N = 2048; break;
  }
  __shared__ float tile[32][33];
  int n0 = blockIdx.x * 32, k0 = blockIdx.y * 32;
  if (n0 >= N || k0 >= K) return;
  int tx = threadIdx.x, ty = threadIdx.y;  // 32 x 8
#pragma unroll
  for (int i = 0; i < 32; i += 8)
    tile[ty + i][tx] = in[(size_t)(k0 + ty + i) * N + n0 + tx];
  __syncthreads();
#pragma unroll
  for (int i = 0; i < 32; i += 8)
    out[(size_t)(n0 + ty + i) * K + k0 + tx] = __float2bfloat16(tile[tx][ty + i]);
}

// ---------------- bf16 MFMA GEMM, 64x128 tile ----------------
__global__ __launch_bounds__(256) void gemm_bf16_64(const __hip_bfloat16* __restrict__ A,
                                                    const __hip_bfloat16* __restrict__ BT,
                                                    float* __restrict__ C, int M, int N, int K) {
  __shared__ __align__(16) __hip_bfloat16 lA[64 * 32];
  __shared__ __align__(16) __hip_bfloat16 lB[128 * 32];
  const int tid = threadIdx.x;
  const int lane = tid & 63;
  const int w = tid >> 6;
  const int row0 = blockIdx.y * 64;
  const int col0 = blockIdx.x * 128;
  f32x4 acc[4][2];
#pragma unroll
  for (int m = 0; m < 4; ++m)
#pragma unroll
    for (int n = 0; n < 2; ++n) acc[m][n] = {0.f, 0.f, 0.f, 0.f};
  const int fr = lane & 15;
  const int ko = (lane >> 4) * 8;
  for (int kt = 0; kt < K; kt += 32) {
    {
      int elem = (w * 64 + lane) * 8;
      int rr = elem >> 5, cc = elem & 31;
      const __hip_bfloat16* srcA = A + (size_t)(row0 + rr) * K + kt + cc;
      __builtin_amdgcn_global_load_lds(AS1(srcA), AS3(&lA[w * 512]), 16, 0, 0);
    }
#pragma unroll
    for (int i = 0; i < 2; ++i) {
      int elem = ((i * 4 + w) * 64 + lane) * 8;
      int rr = elem >> 5, cc = elem & 31;
      const __hip_bfloat16* srcB = BT + (size_t)(col0 + rr) * K + kt + cc;
      __builtin_amdgcn_global_load_lds(AS1(srcB), AS3(&lB[(i * 4 + w) * 512]), 16, 0, 0);
    }
    __syncthreads();
    bf16x8 af[4], bfr[2];
#pragma unroll
    for (int m = 0; m < 4; ++m)
      af[m] = *reinterpret_cast<const bf16x8*>(&lA[(m * 16 + fr) * 32 + ko]);
#pragma unroll
    for (int n = 0; n < 2; ++n)
      bfr[n] = *reinterpret_cast<const bf16x8*>(&lB[(w * 32 + n * 16 + fr) * 32 + ko]);
#pragma unroll
    for (int m = 0; m < 4; ++m)
#pragma unroll
      for (int n = 0; n < 2; ++n)
        acc[m][n] = __builtin_amdgcn_mfma_f32_16x16x32_bf16(af[m], bfr[n], acc[m][n], 0, 0, 0);
    __syncthreads();
  }
  const int rq = (lane >> 4) * 4;
#pragma unroll
  for (int m = 0; m < 4; ++m)
#pragma unroll
    for (int n = 0; n < 2; ++n)
#pragma unroll
      for (int r = 0; r < 4; ++r)
        C[(size_t)(row0 + m * 16 + rq + r) * N + (col0 + w * 32 + n * 16 + fr)] =
            acc[m][n][r];
}

__device__ __forceinline__ float silu_f(float y) { return y / (1.f + __expf(-y)); }

// ---------------- fused x@Wb / x@Wa + beta/g transforms ----------------
__global__ __launch_bounds__(64) void ba_fused_kernel(const float* __restrict__ x,
                                                      const float* __restrict__ Wb,
                                                      const float* __restrict__ Wa,
                                                      const float* __restrict__ A_log,
                                                      const float* __restrict__ dt_bias,
                                                      float* __restrict__ beta_s,
                                                      float* __restrict__ ge_s) {
  const int row = blockIdx.x;
  const int lane = threadIdx.x;
  f32x4 aB0 = {0,0,0,0}, aB1 = {0,0,0,0}, aB2 = {0,0,0,0}, aB3 = {0,0,0,0};
  f32x4 aA0 = {0,0,0,0}, aA1 = {0,0,0,0};
  const float* xr = x + (size_t)row * HID;
  for (int i = 0; i < 32; ++i) {
    int k = lane + i * 64;
    float xv = xr[k];
    const f32x4* wb4 = (const f32x4*)(Wb + (size_t)k * 16);
    const f32x4* wa4 = (const f32x4*)(Wa + (size_t)k * 8);
    aB0 += wb4[0] * xv; aB1 += wb4[1] * xv; aB2 += wb4[2] * xv; aB3 += wb4[3] * xv;
    aA0 += wa4[0] * xv; aA1 += wa4[1] * xv;
  }
  __shared__ float red[64][25];
#pragma unroll
  for (int c = 0; c < 4; ++c) {
    red[lane][0 + c]  = aB0[c];
    red[lane][4 + c]  = aB1[c];
    red[lane][8 + c]  = aB2[c];
    red[lane][12 + c] = aB3[c];
    red[lane][16 + c] = aA0[c];
    red[lane][20 + c] = aA1[c];
  }
  if (lane < 24) {
    float s = 0.f;
#pragma unroll 8
    for (int i = 0; i < 64; ++i) s += red[i][lane];
    int b = row >> 9, t = row & 511;
    if (lane < 16) {
      int j = lane >> 3, h = lane & 7;
      beta_s[(((size_t)(b * 8 + h)) * 2 + j) * 512 + t] = 2.f / (1.f + __expf(-s));
    } else {
      int h = lane - 16;
      float vv = s + dt_bias[h];
      float sp = (vv > 20.f) ? vv : log1pf(__expf(vv));
      ge_s[((size_t)(b * 8 + h)) * 512 + t] = __expf(-__expf(A_log[h]) * sp);
    }
  }
}

// ---------------- fused conv + silu (+l2norm for q/k) for q,k,v ----------------
__global__ __launch_bounds__(128) void conv_qkv_kernel(const float* __restrict__ qkvg,
                                                       const float* __restrict__ wq,
                                                       const float* __restrict__ wk,
                                                       const float* __restrict__ wv,
                                                       float* __restrict__ q_s,
                                                       float* __restrict__ k_s,
                                                       float* __restrict__ v_s) {
  int bt = blockIdx.x;
  int yy = blockIdx.y;
  int d  = threadIdx.x;
  int b = bt >> 9, t = bt & 511;
  __shared__ float red[2];
  if (yy < 8) {
    int h = yy, c = h * 128 + d;
    float y = 0.f;
#pragma unroll
    for (int tau = 0; tau < 4; ++tau) {
      int tt = t - 3 + tau;
      float xv = (tt >= 0) ? qkvg[(size_t)(b * 512 + tt) * NFUSE + c] : 0.f;
      y += xv * wq[c * 4 + tau];
    }
    y = silu_f(y);
    float ss = y * y;
#pragma unroll
    for (int off = 32; off; off >>= 1) ss += __shfl_down(ss, off);
    if ((d & 63) == 0) red[d >> 6] = ss;
    __syncthreads();
    float scale = (1.f / fmaxf(sqrtf(red[0] + red[1]), 1e-12f)) * 0.08838834764831845f;
    q_s[((size_t)(b * 8 + h) * 512 + t) * 128 + d] = y * scale;
  } else if (yy < 24) {
    int jh = yy - 8;
    int j = jh >> 3, h = jh & 7;
    int c = j * 1024 + h * 128 + d;
    float y = 0.f;
#pragma unroll
    for (int tau = 0; tau < 4; ++tau) {
      int tt = t - 3 + tau;
      float xv = (tt >= 0) ? qkvg[(size_t)(b * 512 + tt) * NFUSE + 1024 + c] : 0.f;
      y += xv * wk[c * 4 + tau];
    }
    y = silu_f(y);
    float ss = y * y;
#pragma unroll
    for (int off = 32; off; off >>= 1) ss += __shfl_down(ss, off);
    if ((d & 63) == 0) red[d >> 6] = ss;
    __syncthreads();
    float scale = 1.f / fmaxf(sqrtf(red[0] + red[1]), 1e-12f);
    k_s[(((size_t)(b * 8 + h) * 2 + j) * 512 + t) * 128 + d] = y * scale;
  } else {
    int jh = yy - 24;
    int j = jh >> 3, h = jh & 7;
    int c = j * 1024 + h * 128 + d;
    float y = 0.f;
#pragma unroll
    for (int tau = 0; tau < 4; ++tau) {
      int tt = t - 3 + tau;
      float xv = (tt >= 0) ? qkvg[(size_t)(b * 512 + tt) * NFUSE + 3072 + c] : 0.f;
      y += xv * wv[c * 4 + tau];
    }
    v_s[(((size_t)(b * 8 + h) * 2 + j) * 512 + t) * 128 + d] = silu_f(y);
  }
}

// ---------------- pair cross-dots + packed per-pair scalars ----------------
// spack[bh][pair][20] = {gA,gB,b0A,b1A, b0B,b1B,d01A,dq0A, dq1A,d01B,dq0B,dq1B,
//                        c00,c01,c10,c11, cq0,cq1, pad,pad}
__global__ __launch_bounds__(64) void dots_kernel(const float* __restrict__ q_s,
                                                  const float* __restrict__ k_s,
                                                  const float* __restrict__ beta_s,
                                                  const float* __restrict__ ge_s,
                                                  float* __restrict__ spack) {
  const int bh = blockIdx.x;     // 0..15
  const int py = blockIdx.y;     // 0..31
  const int lane = threadIdx.x;
  const int e  = lane & 7;
  const int pl = lane >> 3;
  const int p = py * 8 + pl;
  const int tA = 2 * p;
  const float* k0A = k_s + ((size_t)bh * 2 + 0) * 512 * 128 + (size_t)tA * 128 + e * 16;
  const float* k1A = k_s + ((size_t)bh * 2 + 1) * 512 * 128 + (size_t)tA * 128 + e * 16;
  const float* qA  = q_s + (size_t)bh * 512 * 128 + (size_t)tA * 128 + e * 16;
  float d0=0,d1=0,d2=0,d3=0,d4=0,d5=0,d6=0,d7=0,d8=0,d9=0,d10=0,d11=0;
#pragma unroll
  for (int i = 0; i < 4; ++i) {
    f32x4 a0 = *(const f32x4*)(k0A + i * 4);
    f32x4 a1 = *(const f32x4*)(k1A + i * 4);
    f32x4 qa = *(const f32x4*)(qA  + i * 4);
    f32x4 b0 = *(const f32x4*)(k0A + 128 + i * 4);
    f32x4 b1 = *(const f32x4*)(k1A + 128 + i * 4);
    f32x4 qb = *(const f32x4*)(qA  + 128 + i * 4);
    f32x4 t;
#define HS(acc, u, w) t = (u) * (w); acc += (t[0] + t[1]) + (t[2] + t[3]);
    HS(d0, a1, a0) HS(d1, qa, a0) HS(d2, qa, a1)
    HS(d3, b1, b0) HS(d4, qb, b0) HS(d5, qb, b1)
    HS(d6, b0, a0) HS(d7, b0, a1) HS(d8, b1, a0) HS(d9, b1, a1)
    HS(d10, qb, a0) HS(d11, qb, a1)
#undef HS
  }
#define RED(dd) dd += dpp_xor1(dd); dd += dpp_xor2(dd); dd += dpp_hmirror(dd);
  RED(d0) RED(d1) RED(d2) RED(d3) RED(d4) RED(d5)
  RED(d6) RED(d7) RED(d8) RED(d9) RED(d10) RED(d11)
#undef RED
  if (e == 0) {
    const float* b0p = beta_s + ((size_t)bh * 2 + 0) * 512;
    const float* b1p = beta_s + ((size_t)bh * 2 + 1) * 512;
    const float* gp  = ge_s + (size_t)bh * 512;
    float* dst = spack + ((size_t)bh * 256 + p) * 20;
    dst[0] = gp[tA];      dst[1] = gp[tA + 1];
    dst[2] = b0p[tA];     dst[3] = b1p[tA];
    dst[4] = b0p[tA + 1]; dst[5] = b1p[tA + 1];
    dst[6] = d0;  dst[7] = d1;  dst[8] = d2;  dst[9] = d3;
    dst[10] = d4; dst[11] = d5; dst[12] = d6; dst[13] = d7;
    dst[14] = d8; dst[15] = d9; dst[16] = d10; dst[17] = d11;
  }
}

// ---------------- scan: dual-chain interleave (2 chains per wave) ----------------
// 256 blocks x 64 thr = 8 chain-PAIRS x 32 v-groups. Each wave runs chains
// X=2cp, Y=2cp+1 with interleaved COMPUTE blocks (no sched_barrier between):
// the compiler fills chain-X's dep-chain/DPP-hazard bubbles with chain-Y's
// instructions (round-11/12 lesson: per-wave stall fraction ~53% was the
// residual; waves/SIMD can't exceed 1, so fill stalls IN-wave).
// TSTEP=4, scalars read directly from packed global spack (prefetched a
// phase ahead), LDS 37.5KB, VGPR budget ~390 (<512 OK at 1 wave/SIMD).
#define CH 12
#define TILEF4 (4 * 3 * 16 * CH)   // 2304 floats per buffer per chain

__global__ __launch_bounds__(64, 1) void scan_kernel(const float* __restrict__ q_s,
                                                     const float* __restrict__ k_s,
                                                     const float* __restrict__ v_s,
                                                     const float* __restrict__ spack,
                                                     float* __restrict__ o_s,
                                                     float* __restrict__ state_out) {
  const int blk = blockIdx.x;      // 0..255
  const int cp  = blk >> 5;        // chain-pair 0..7
  const int wg  = blk & 31;        // v-group 0..31
  const int lane = threadIdx.x;
  const int kr = lane & 15;
  const int vi = lane >> 4;
  const int v  = wg * 4 + vi;
  const int bhX = cp * 2, bhY = cp * 2 + 1;

  __shared__ __align__(16) float ldsX[2][TILEF4];
  __shared__ __align__(16) float ldsY[2][TILEF4];
  __shared__ __align__(16) float vbufX[2][2][4][4];
  __shared__ __align__(16) float vbufY[2][2][4][4];

  f32x4 s0X = {0,0,0,0}, s1X = {0,0,0,0};
  f32x4 s0Y = {0,0,0,0}, s1Y = {0,0,0,0};
  f32x4 G0X_0, G0X_1, G1X_0, G1X_1, G2X_0, G2X_1;
  f32x4 G0Y_0, G0Y_1, G1Y_0, G1Y_1, G2Y_0, G2Y_1;
  float GvX, GvY;
#define DECLSET(S) f32x4 S##_a0A,S##_a1A,S##_b0A,S##_b1A,S##_c0A,S##_c1A, \
                         S##_a0B,S##_a1B,S##_b0B,S##_b1B,S##_c0B,S##_c1B; \
  float S##_gA,S##_gB,S##_bb0A,S##_bb1A,S##_bb0B,S##_bb1B, \
        S##_d01A,S##_dq0A,S##_dq1A,S##_d01B,S##_dq0B,S##_dq1B, \
        S##_c00,S##_c01,S##_c10,S##_c11,S##_cq0,S##_cq1, \
        S##_mv0A,S##_mv1A,S##_mv0B,S##_mv1B;
  DECLSET(XA) DECLSET(XB) DECLSET(YA) DECLSET(YB)
#undef DECLSET

  const float* g_k0X = k_s + ((size_t)bhX * 2 + 0) * 512 * 128;
  const float* g_k1X = k_s + ((size_t)bhX * 2 + 1) * 512 * 128;
  const float* g_qX  = q_s + (size_t)bhX * 512 * 128;
  const float* g_k0Y = k_s + ((size_t)bhY * 2 + 0) * 512 * 128;
  const float* g_k1Y = k_s + ((size_t)bhY * 2 + 1) * 512 * 128;
  const float* g_qY  = q_s + (size_t)bhY * 512 * 128;
  const float* spX = spack + (size_t)bhX * 256 * 20;
  const float* spY = spack + (size_t)bhY * 256 * 20;

  const int vhalf = lane >> 5;
  const int vli = lane & 31;
  const int vtlc = (vli >> 2) & 3, vc = vli & 3;
  const float* vsrcX = v_s + ((size_t)bhX * 2 + vhalf) * 512 * 128 + wg * 4;
  const float* vsrcY = v_s + ((size_t)bhY * 2 + vhalf) * 512 * 128 + wg * 4;

#define LOAD_G(C, T) { \
    const f32x4* p0_ = (const f32x4*)(g_k0##C + (size_t)(T) * 512); \
    const f32x4* p1_ = (const f32x4*)(g_k1##C + (size_t)(T) * 512); \
    const f32x4* pq_ = (const f32x4*)(g_q##C  + (size_t)(T) * 512); \
    G0##C##_0 = p0_[lane]; G0##C##_1 = p0_[lane + 64]; \
    G1##C##_0 = p1_[lane]; G1##C##_1 = p1_[lane + 64]; \
    G2##C##_0 = pq_[lane]; G2##C##_1 = pq_[lane + 64]; }
#define LOAD_V(C, T) { Gv##C = vsrc##C[((size_t)(T) * 4 + vtlc) * 128 + vc]; }
#define WRG1(C, b, j) { int g_ = lane + 64 * (j); int tl_ = g_ >> 5; int r4_ = g_ & 31; \
    int kr_ = r4_ >> 1; int c_ = (r4_ & 1) * 4; \
    *(f32x4*)&lds##C[b][((tl_ * 3 + 0) * 16 + kr_) * CH + c_] = G0##C##_##j; \
    *(f32x4*)&lds##C[b][((tl_ * 3 + 1) * 16 + kr_) * CH + c_] = G1##C##_##j; \
    *(f32x4*)&lds##C[b][((tl_ * 3 + 2) * 16 + kr_) * CH + c_] = G2##C##_##j; }
#define WRITE_G(C, b) { WRG1(C, b, 0) WRG1(C, b, 1) }
#define WRITE_V(C, b) { if (vli < 16) vbuf##C[b][vhalf][vtlc][vc] = Gv##C; }

#define LOAD_PAIR(CS, C, bufx, tlx, pg) { \
    const f32x4* pk0A_ = (const f32x4*)&lds##C[bufx][(((tlx) * 3 + 0) * 16 + kr) * CH]; \
    const f32x4* pk1A_ = (const f32x4*)&lds##C[bufx][(((tlx) * 3 + 1) * 16 + kr) * CH]; \
    const f32x4* pqA_  = (const f32x4*)&lds##C[bufx][(((tlx) * 3 + 2) * 16 + kr) * CH]; \
    const f32x4* pk0B_ = (const f32x4*)&lds##C[bufx][((((tlx) + 1) * 3 + 0) * 16 + kr) * CH]; \
    const f32x4* pk1B_ = (const f32x4*)&lds##C[bufx][((((tlx) + 1) * 3 + 1) * 16 + kr) * CH]; \
    const f32x4* pqB_  = (const f32x4*)&lds##C[bufx][((((tlx) + 1) * 3 + 2) * 16 + kr) * CH]; \
    CS##_a0A = pk0A_[0]; CS##_a1A = pk0A_[1]; \
    CS##_b0A = pk1A_[0]; CS##_b1A = pk1A_[1]; \
    CS##_c0A = pqA_[0];  CS##_c1A = pqA_[1]; \
    CS##_a0B = pk0B_[0]; CS##_a1B = pk0B_[1]; \
    CS##_b0B = pk1B_[0]; CS##_b1B = pk1B_[1]; \
    CS##_c0B = pqB_[0];  CS##_c1B = pqB_[1]; \
    const f32x4* sc_ = (const f32x4*)(sp##C + (size_t)((pg) & 255) * 20); \
    f32x4 y0_ = sc_[0], y1_ = sc_[1], y2_ = sc_[2], y3_ = sc_[3], y4_ = sc_[4]; \
    CS##_gA = y0_[0]; CS##_gB = y0_[1]; CS##_bb0A = y0_[2]; CS##_bb1A = y0_[3]; \
    CS##_bb0B = y1_[0]; CS##_bb1B = y1_[1]; CS##_d01A = y1_[2]; CS##_dq0A = y1_[3]; \
    CS##_dq1A = y2_[0]; CS##_d01B = y2_[1]; CS##_dq0B = y2_[2]; CS##_dq1B = y2_[3]; \
    CS##_c00 = y3_[0]; CS##_c01 = y3_[1]; CS##_c10 = y3_[2]; CS##_c11 = y3_[3]; \
    CS##_cq0 = y4_[0]; CS##_cq1 = y4_[1]; \
    CS##_mv0A = vbuf##C[bufx][0][tlx][vi]; CS##_mv1A = vbuf##C[bufx][1][tlx][vi]; \
    CS##_mv0B = vbuf##C[bufx][0][(tlx) + 1][vi]; CS##_mv1B = vbuf##C[bufx][1][(tlx) + 1][vi]; }

#define COMPUTE_PAIR(CS, C, pg) { \
    f32x4 r0A_ = CS##_a0A * s0##C; r0A_ += CS##_a1A * s1##C; \
    f32x4 r1A_ = CS##_b0A * s0##C; r1A_ += CS##_b1A * s1##C; \
    f32x4 rqA_ = CS##_c0A * s0##C; rqA_ += CS##_c1A * s1##C; \
    f32x4 r0B_ = CS##_a0B * s0##C; r0B_ += CS##_a1B * s1##C; \
    f32x4 r1B_ = CS##_b0B * s0##C; r1B_ += CS##_b1B * s1##C; \
    f32x4 rqB_ = CS##_c0B * s0##C; rqB_ += CS##_c1B * s1##C; \
    float h0A = (r0A_[0] + r0A_[1]) + (r0A_[2] + r0A_[3]); \
    float h1A = (r1A_[0] + r1A_[1]) + (r1A_[2] + r1A_[3]); \
    float hqA = (rqA_[0] + rqA_[1]) + (rqA_[2] + rqA_[3]); \
    float h0B = (r0B_[0] + r0B_[1]) + (r0B_[2] + r0B_[3]); \
    float h1B = (r1B_[0] + r1B_[1]) + (r1B_[2] + r1B_[3]); \
    float hqB = (rqB_[0] + rqB_[1]) + (rqB_[2] + rqB_[3]); \
    h0A += dpp_xor1(h0A); h1A += dpp_xor1(h1A); hqA += dpp_xor1(hqA); \
    h0B += dpp_xor1(h0B); h1B += dpp_xor1(h1B); hqB += dpp_xor1(hqB); \
    h0A += dpp_xor2(h0A); h1A += dpp_xor2(h1A); hqA += dpp_xor2(hqA); \
    h0B += dpp_xor2(h0B); h1B += dpp_xor2(h1B); hqB += dpp_xor2(hqB); \
    h0A += dpp_hmirror(h0A); h1A += dpp_hmirror(h1A); hqA += dpp_hmirror(hqA); \
    h0B += dpp_hmirror(h0B); h1B += dpp_hmirror(h1B); hqB += dpp_hmirror(hqB); \
    h0A += dpp_rmirror(h0A); h1A += dpp_rmirror(h1A); hqA += dpp_rmirror(hqA); \
    h0B += dpp_rmirror(h0B); h1B += dpp_rmirror(h1B); hqB += dpp_rmirror(hqB); \
    const float u0A_ = (CS##_mv0A - CS##_gA * h0A) * CS##_bb0A; \
    const float u1A_ = (CS##_mv1A - CS##_gA * h1A - CS##_d01A * u0A_) * CS##_bb1A; \
    const float u0B_ = (CS##_mv0B - CS##_gB * (CS##_gA * h0B + CS##_c00 * u0A_ + CS##_c01 * u1A_)) * CS##_bb0B; \
    const float u1B_ = (CS##_mv1B - CS##_gB * (CS##_gA * h1B + CS##_c10 * u0A_ + CS##_c11 * u1A_) \
                        - CS##_d01B * u0B_) * CS##_bb1B; \
    const float oA_ = CS##_gA * hqA + CS##_dq0A * u0A_ + CS##_dq1A * u1A_; \
    const float oB_ = CS##_gB * (CS##_gA * hqB + CS##_cq0 * u0A_ + CS##_cq1 * u1A_) \
                      + CS##_dq0B * u0B_ + CS##_dq1B * u1B_; \
    const float gg_ = CS##_gA * CS##_gB; \
    const float w0_ = CS##_gB * u0A_, w1_ = CS##_gB * u1A_; \
    s0##C *= gg_; s0##C += CS##_a0A * w0_; s0##C += CS##_b0A * w1_; \
    s0##C += CS##_a0B * u0B_; s0##C += CS##_b0B * u1B_; \
    s1##C *= gg_; s1##C += CS##_a1A * w0_; s1##C += CS##_b1A * w1_; \
    s1##C += CS##_a1B * u0B_; s1##C += CS##_b1B * u1B_; \
    if (kr == 0) { const int tA_ = 2 * (pg); \
      o_s[((size_t)bh##C * 512 + tA_) * 128 + v] = oA_; \
      o_s[((size_t)bh##C * 512 + tA_ + 1) * 128 + v] = oB_; } }

  LOAD_G(X, 0) LOAD_V(X, 0) LOAD_G(Y, 0) LOAD_V(Y, 0)
  WRITE_G(X, 0) WRITE_V(X, 0) WRITE_G(Y, 0) WRITE_V(Y, 0)
  LOAD_G(X, 1) LOAD_V(X, 1) LOAD_G(Y, 1) LOAD_V(Y, 1)
  LOAD_PAIR(XA, X, 0, 0, 0) LOAD_PAIR(YA, Y, 0, 0, 0)
  __builtin_amdgcn_sched_barrier(0);

  for (int T = 0; T < 128; ++T) {
    const int buf = T & 1;
    if (T < 127) { WRITE_G(X, buf ^ 1) WRITE_V(X, buf ^ 1)
                   WRITE_G(Y, buf ^ 1) WRITE_V(Y, buf ^ 1) }
    const int p0i = T * 2;
    LOAD_PAIR(XB, X, buf, 2, p0i + 1) LOAD_PAIR(YB, Y, buf, 2, p0i + 1)
    __builtin_amdgcn_sched_barrier(0);
    COMPUTE_PAIR(XA, X, p0i) COMPUTE_PAIR(YA, Y, p0i)
    if (T < 126) { LOAD_G(X, T + 2) LOAD_V(X, T + 2)
                   LOAD_G(Y, T + 2) LOAD_V(Y, T + 2) }
    LOAD_PAIR(XA, X, buf ^ 1, 0, (p0i + 2) & 255) LOAD_PAIR(YA, Y, buf ^ 1, 0, (p0i + 2) & 255)
    __builtin_amdgcn_sched_barrier(0);
    COMPUTE_PAIR(XB, X, p0i + 1) COMPUTE_PAIR(YB, Y, p0i + 1)
  }

  {
    float* baseX = state_out + (size_t)bhX * 128 * 128 + v;
    float* baseY = state_out + (size_t)bhY * 128 * 128 + v;
#pragma unroll
    for (int i = 0; i < 4; ++i) {
      baseX[(kr * 8 + i) * 128]     = s0X[i];
      baseX[(kr * 8 + 4 + i) * 128] = s1X[i];
      baseY[(kr * 8 + i) * 128]     = s0Y[i];
      baseY[(kr * 8 + 4 + i) * 128] = s1Y[i];
    }
  }
}

// ---------------- rmsnorm + gate silu -> bf16 A for final GEMM ----------------
__global__ __launch_bounds__(128) void post_kernel(const float* __restrict__ o_s,
                                                   const float* __restrict__ qkvg,
                                                   const float* __restrict__ norm_w,
                                                   __hip_bfloat16* __restrict__ Afin) {
  int bt = blockIdx.x;
  int h = blockIdx.y;
  int d = threadIdx.x;
  int b = bt >> 9, t = bt & 511;
  int bh = b * 8 + h;
  float o = o_s[((size_t)bh * 512 + t) * 128 + d];
  __shared__ float red[2];
  float ss = o * o;
#pragma unroll
  for (int off = 32; off; off >>= 1) ss += __shfl_down(ss, off);
  if ((d & 63) == 0) red[d >> 6] = ss;
  __syncthreads();
  float mean = (red[0] + red[1]) * (1.f / 128.f);
  float r = rsqrtf(mean + 1e-5f);
  float gate = qkvg[(size_t)bt * NFUSE + 5120 + h * 128 + d];
  float val = o * r * norm_w[d] * silu_f(gate);
  Afin[(size_t)bt * 1024 + h * 128 + d] = __float2bfloat16(val);
}

extern "C" void kernel_launch(void* const* d_in, const int* in_sizes, int n_in,
                              void* d_out, int out_size, void* d_ws, size_t ws_size,
                              hipStream_t stream) {
  const float* x       = (const float*)d_in[0];
  const float* Wq      = (const float*)d_in[1];
  const float* Wk      = (const float*)d_in[2];
  const float* Wv      = (const float*)d_in[3];
  const float* Wb      = (const float*)d_in[4];
  const float* Wa      = (const float*)d_in[5];
  const float* A_log   = (const float*)d_in[6];
  const float* dt_bias = (const float*)d_in[7];
  const float* cqw     = (const float*)d_in[8];
  const float* ckw     = (const float*)d_in[9];
  const float* cvw     = (const float*)d_in[10];
  const float* Wg      = (const float*)d_in[11];
  const float* norm_w  = (const float*)d_in[12];
  const float* Wo      = (const float*)d_in[13];

  char* ws = (char*)d_ws;
  size_t off = 0;
  auto alloc = [&](size_t bytes) {
    void* p = ws + off;
    off += (bytes + 255) & ~(size_t)255;
    return p;
  };
  __hip_bfloat16* xbf  = (__hip_bfloat16*)alloc((size_t)2097152 * 2);
  __hip_bfloat16* WT   = (__hip_bfloat16*)alloc((size_t)NFUSE * 2048 * 2);
  __hip_bfloat16* WoT  = (__hip_bfloat16*)alloc((size_t)2097152 * 2);
  float* qkvg   = (float*)alloc((size_t)ROWS * NFUSE * 4);
  float* q_s    = (float*)alloc((size_t)1048576 * 4);
  float* k_s    = (float*)alloc((size_t)2097152 * 4);
  float* v_s    = (float*)alloc((size_t)2097152 * 4);
  float* beta_s = (float*)alloc((size_t)16384 * 4);
  float* ge_s   = (float*)alloc((size_t)8192 * 4);
  float* spack  = (float*)alloc((size_t)16 * 256 * 20 * 4);
  float* o_s    = (float*)alloc((size_t)1048576 * 4);
  __hip_bfloat16* Afin = (__hip_bfloat16*)alloc((size_t)1048576 * 2);

  float* out_main  = (float*)d_out;
  float* out_state = out_main + 2097152;

  dim3 tb(32, 8);
  f2bf_kernel<<<8192, 256, 0, stream>>>(x, xbf, 2097152);
  transpose5_kernel<<<dim3(64, 64, 5), tb, 0, stream>>>(Wq, Wk, Wv, Wg, Wo, WT, WoT);

  gemm_bf16_64<<<dim3(48, 16), 256, 0, stream>>>(xbf, WT, qkvg, 1024, NFUSE, 2048);
  ba_fused_kernel<<<1024, 64, 0, stream>>>(x, Wb, Wa, A_log, dt_bias, beta_s, ge_s);

  conv_qkv_kernel<<<dim3(1024, 40), 128, 0, stream>>>(qkvg, cqw, ckw, cvw, q_s, k_s, v_s);
  dots_kernel<<<dim3(16, 32), 64, 0, stream>>>(q_s, k_s, beta_s, ge_s, spack);

  scan_kernel<<<256, 64, 0, stream>>>(q_s, k_s, v_s, spack, o_s, out_state);

  post_kernel<<<dim3(1024, 8), 128, 0, stream>>>(o_s, qkvg, norm_w, Afin);
  gemm_bf16_64<<<dim3(16, 16), 256, 0, stream>>>(Afin, WoT, out_main, 1024, 2048, 1024);
}

// Round 14
// 241.456 us; speedup vs baseline: 1.5591x; 1.5591x over previous
//
#include <hip/hip_runtime.h>
#include <hip/hip_bf16.h>
#include <cmath>

#define B_   2
#define L_   512
#define HID  2048
#define DH   128
#define NH   8
#define NHH  2
#define ROWS 1024  // B_*L_
#define NFUSE 6144 // 1024(q)+2048(k)+2048(v)+1024(g)

typedef float  f32x2  __attribute__((ext_vector_type(2)));
typedef float  f32x4  __attribute__((ext_vector_type(4)));
typedef __bf16 bf16x8 __attribute__((ext_vector_type(8)));

#define AS1(p) ((const __attribute__((address_space(1))) unsigned int*)(p))
#define AS3(p) ((__attribute__((address_space(3))) unsigned int*)(p))

__device__ __forceinline__ float dpp_xor1(float x) {
  int r = __builtin_amdgcn_update_dpp(0, __float_as_int(x), 0xB1, 0xF, 0xF, true);
  return __int_as_float(r);
}
__device__ __forceinline__ float dpp_xor2(float x) {
  int r = __builtin_amdgcn_update_dpp(0, __float_as_int(x), 0x4E, 0xF, 0xF, true);
  return __int_as_float(r);
}
__device__ __forceinline__ float dpp_hmirror(float x) {  // mirror within 8
  int r = __builtin_amdgcn_update_dpp(0, __float_as_int(x), 0x141, 0xF, 0xF, true);
  return __int_as_float(r);
}
__device__ __forceinline__ float dpp_rmirror(float x) {  // mirror within 16
  int r = __builtin_amdgcn_update_dpp(0, __float_as_int(x), 0x140, 0xF, 0xF, true);
  return __int_as_float(r);
}

// ---------------- f32 -> bf16 elementwise ----------------
__global__ void f2bf_kernel(const float* __restrict__ in, __hip_bfloat16* __restrict__ out, int n) {
  int i = blockIdx.x * 256 + threadIdx.x;
  if (i < n) out[i] = __float2bfloat16(in[i]);
}

// ---------------- 5 weight transposes in one dispatch (blockIdx.z selects) -------
__global__ __launch_bounds__(256) void transpose5_kernel(const float* __restrict__ Wq,
                                                         const float* __restrict__ Wk,
                                                         const float* __restrict__ Wv,
                                                         const float* __restrict__ Wg,
                                                         const float* __restrict__ Wo,
                                                         __hip_bfloat16* __restrict__ WT,
                                                         __hip_bfloat16* __restrict__ WoT) {
  const float* in; __hip_bfloat16* out; int K, N;
  switch (blockIdx.z) {
    case 0: in = Wq; out = WT;                          K = 2048; N = 1024; break;
    case 1: in = Wk; out = WT + (size_t)1024 * 2048;    K = 2048; N = 2048; break;
    case 2: in = Wv; out = WT + (size_t)3072 * 2048;    K = 2048; N = 2048; break;
    case 3: in = Wg; out = WT + (size_t)5120 * 2048;    K = 2048; N = 1024; break;
    default: in = Wo; out = WoT;                        K = 1024; N = 2048; break;
  }
  __shared__ float tile[32][33];
  int n0 = blockIdx.x * 32, k0 = blockIdx.y * 32;
  if (n0 >= N || k0 >= K) return;
  int tx = threadIdx.x, ty = threadIdx.y;  // 32 x 8
#pragma unroll
  for (int i = 0; i < 32; i += 8)
    tile[ty + i][tx] = in[(size_t)(k0 + ty + i) * N + n0 + tx];
  __syncthreads();
#pragma unroll
  for (int i = 0; i < 32; i += 8)
    out[(size_t)(n0 + ty + i) * K + k0 + tx] = __float2bfloat16(tile[tx][ty + i]);
}

// ---------------- bf16 MFMA GEMM, 64x128 tile: C(MxN) = A(MxK) * BT(NxK)^T -------
// BM=64 BN=128 BK=32, 256 thr = 4 waves; wave w owns 64x32 output (cols w*32..),
// frags 4(m) x 2(n) of 16x16x32. 64-row tiles give 768 / 256 blocks =
// balanced 3 / 1 blocks per CU (vs 1.5 / 0.5 with 128x128).
__global__ __launch_bounds__(256) void gemm_bf16_64(const __hip_bfloat16* __restrict__ A,
                                                    const __hip_bfloat16* __restrict__ BT,
                                                    float* __restrict__ C, int M, int N, int K) {
  __shared__ __align__(16) __hip_bfloat16 lA[64 * 32];
  __shared__ __align__(16) __hip_bfloat16 lB[128 * 32];
  const int tid = threadIdx.x;
  const int lane = tid & 63;
  const int w = tid >> 6;          // wave 0..3 = output col block
  const int row0 = blockIdx.y * 64;
  const int col0 = blockIdx.x * 128;
  f32x4 acc[4][2];
#pragma unroll
  for (int m = 0; m < 4; ++m)
#pragma unroll
    for (int n = 0; n < 2; ++n) acc[m][n] = {0.f, 0.f, 0.f, 0.f};
  const int fr = lane & 15;
  const int ko = (lane >> 4) * 8;
  for (int kt = 0; kt < K; kt += 32) {
    {  // stage A: 2048 elems, one 16B/lane load per wave
      int elem = (w * 64 + lane) * 8;
      int rr = elem >> 5, cc = elem & 31;
      const __hip_bfloat16* srcA = A + (size_t)(row0 + rr) * K + kt + cc;
      __builtin_amdgcn_global_load_lds(AS1(srcA), AS3(&lA[w * 512]), 16, 0, 0);
    }
#pragma unroll
    for (int i = 0; i < 2; ++i) {  // stage B: 4096 elems, two loads per wave
      int elem = ((i * 4 + w) * 64 + lane) * 8;
      int rr = elem >> 5, cc = elem & 31;
      const __hip_bfloat16* srcB = BT + (size_t)(col0 + rr) * K + kt + cc;
      __builtin_amdgcn_global_load_lds(AS1(srcB), AS3(&lB[(i * 4 + w) * 512]), 16, 0, 0);
    }
    __syncthreads();
    bf16x8 af[4], bfr[2];
#pragma unroll
    for (int m = 0; m < 4; ++m)
      af[m] = *reinterpret_cast<const bf16x8*>(&lA[(m * 16 + fr) * 32 + ko]);
#pragma unroll
    for (int n = 0; n < 2; ++n)
      bfr[n] = *reinterpret_cast<const bf16x8*>(&lB[(w * 32 + n * 16 + fr) * 32 + ko]);
#pragma unroll
    for (int m = 0; m < 4; ++m)
#pragma unroll
      for (int n = 0; n < 2; ++n)
        acc[m][n] = __builtin_amdgcn_mfma_f32_16x16x32_bf16(af[m], bfr[n], acc[m][n], 0, 0, 0);
    __syncthreads();
  }
  const int rq = (lane >> 4) * 4;
#pragma unroll
  for (int m = 0; m < 4; ++m)
#pragma unroll
    for (int n = 0; n < 2; ++n)
#pragma unroll
      for (int r = 0; r < 4; ++r)
        C[(size_t)(row0 + m * 16 + rq + r) * N + (col0 + w * 32 + n * 16 + fr)] =
            acc[m][n][r];
}

__device__ __forceinline__ float silu_f(float y) { return y / (1.f + __expf(-y)); }

// ---------------- fused x@Wb / x@Wa + beta/g transforms (one block per row) ------
__global__ __launch_bounds__(64) void ba_fused_kernel(const float* __restrict__ x,
                                                      const float* __restrict__ Wb,
                                                      const float* __restrict__ Wa,
                                                      const float* __restrict__ A_log,
                                                      const float* __restrict__ dt_bias,
                                                      float* __restrict__ beta_s,
                                                      float* __restrict__ ge_s) {
  const int row = blockIdx.x;   // b*512 + t
  const int lane = threadIdx.x;
  f32x4 aB0 = {0,0,0,0}, aB1 = {0,0,0,0}, aB2 = {0,0,0,0}, aB3 = {0,0,0,0};
  f32x4 aA0 = {0,0,0,0}, aA1 = {0,0,0,0};
  const float* xr = x + (size_t)row * HID;
  for (int i = 0; i < 32; ++i) {
    int k = lane + i * 64;
    float xv = xr[k];
    const f32x4* wb4 = (const f32x4*)(Wb + (size_t)k * 16);
    const f32x4* wa4 = (const f32x4*)(Wa + (size_t)k * 8);
    aB0 += wb4[0] * xv; aB1 += wb4[1] * xv; aB2 += wb4[2] * xv; aB3 += wb4[3] * xv;
    aA0 += wa4[0] * xv; aA1 += wa4[1] * xv;
  }
  __shared__ float red[64][25];
#pragma unroll
  for (int c = 0; c < 4; ++c) {
    red[lane][0 + c]  = aB0[c];
    red[lane][4 + c]  = aB1[c];
    red[lane][8 + c]  = aB2[c];
    red[lane][12 + c] = aB3[c];
    red[lane][16 + c] = aA0[c];
    red[lane][20 + c] = aA1[c];
  }
  // single wave: in-order LDS, no barrier needed
  if (lane < 24) {
    float s = 0.f;
#pragma unroll 8
    for (int i = 0; i < 64; ++i) s += red[i][lane];
    int b = row >> 9, t = row & 511;
    if (lane < 16) {
      int j = lane >> 3, h = lane & 7;
      beta_s[(((size_t)(b * 8 + h)) * 2 + j) * 512 + t] = 2.f / (1.f + __expf(-s));
    } else {
      int h = lane - 16;
      float vv = s + dt_bias[h];
      float sp = (vv > 20.f) ? vv : log1pf(__expf(vv));
      ge_s[((size_t)(b * 8 + h)) * 512 + t] = __expf(-__expf(A_log[h]) * sp);
    }
  }
}

// ---------------- fused conv + silu (+l2norm for q/k) for q,k,v ----------------
__global__ __launch_bounds__(128) void conv_qkv_kernel(const float* __restrict__ qkvg,
                                                       const float* __restrict__ wq,
                                                       const float* __restrict__ wk,
                                                       const float* __restrict__ wv,
                                                       float* __restrict__ q_s,
                                                       float* __restrict__ k_s,
                                                       float* __restrict__ v_s) {
  int bt = blockIdx.x;
  int yy = blockIdx.y;
  int d  = threadIdx.x;
  int b = bt >> 9, t = bt & 511;
  __shared__ float red[2];
  if (yy < 8) {
    int h = yy, c = h * 128 + d;
    float y = 0.f;
#pragma unroll
    for (int tau = 0; tau < 4; ++tau) {
      int tt = t - 3 + tau;
      float xv = (tt >= 0) ? qkvg[(size_t)(b * 512 + tt) * NFUSE + c] : 0.f;
      y += xv * wq[c * 4 + tau];
    }
    y = silu_f(y);
    float ss = y * y;
#pragma unroll
    for (int off = 32; off; off >>= 1) ss += __shfl_down(ss, off);
    if ((d & 63) == 0) red[d >> 6] = ss;
    __syncthreads();
    float scale = (1.f / fmaxf(sqrtf(red[0] + red[1]), 1e-12f)) * 0.08838834764831845f;
    q_s[((size_t)(b * 8 + h) * 512 + t) * 128 + d] = y * scale;
  } else if (yy < 24) {
    int jh = yy - 8;
    int j = jh >> 3, h = jh & 7;
    int c = j * 1024 + h * 128 + d;
    float y = 0.f;
#pragma unroll
    for (int tau = 0; tau < 4; ++tau) {
      int tt = t - 3 + tau;
      float xv = (tt >= 0) ? qkvg[(size_t)(b * 512 + tt) * NFUSE + 1024 + c] : 0.f;
      y += xv * wk[c * 4 + tau];
    }
    y = silu_f(y);
    float ss = y * y;
#pragma unroll
    for (int off = 32; off; off >>= 1) ss += __shfl_down(ss, off);
    if ((d & 63) == 0) red[d >> 6] = ss;
    __syncthreads();
    float scale = 1.f / fmaxf(sqrtf(red[0] + red[1]), 1e-12f);
    k_s[(((size_t)(b * 8 + h) * 2 + j) * 512 + t) * 128 + d] = y * scale;
  } else {
    int jh = yy - 24;
    int j = jh >> 3, h = jh & 7;
    int c = j * 1024 + h * 128 + d;
    float y = 0.f;
#pragma unroll
    for (int tau = 0; tau < 4; ++tau) {
      int tt = t - 3 + tau;
      float xv = (tt >= 0) ? qkvg[(size_t)(b * 512 + tt) * NFUSE + 3072 + c] : 0.f;
      y += xv * wv[c * 4 + tau];
    }
    v_s[(((size_t)(b * 8 + h) * 2 + j) * 512 + t) * 128 + d] = silu_f(y);
  }
}

// ---------------- pair cross-dots (input-only), 12 scalars per pair p=t/2 -------
__global__ __launch_bounds__(64) void dots_kernel(const float* __restrict__ q_s,
                                                  const float* __restrict__ k_s,
                                                  float* __restrict__ dots_s) {
  const int bh = blockIdx.x;     // 0..15
  const int py = blockIdx.y;     // 0..31
  const int lane = threadIdx.x;
  const int e  = lane & 7;       // 16-float slice
  const int pl = lane >> 3;      // pair-in-block 0..7
  const int p = py * 8 + pl;     // pair 0..255
  const int tA = 2 * p;
  const float* k0A = k_s + ((size_t)bh * 2 + 0) * 512 * 128 + (size_t)tA * 128 + e * 16;
  const float* k1A = k_s + ((size_t)bh * 2 + 1) * 512 * 128 + (size_t)tA * 128 + e * 16;
  const float* qA  = q_s + (size_t)bh * 512 * 128 + (size_t)tA * 128 + e * 16;
  float d0=0,d1=0,d2=0,d3=0,d4=0,d5=0,d6=0,d7=0,d8=0,d9=0,d10=0,d11=0;
#pragma unroll
  for (int i = 0; i < 4; ++i) {
    f32x4 a0 = *(const f32x4*)(k0A + i * 4);
    f32x4 a1 = *(const f32x4*)(k1A + i * 4);
    f32x4 qa = *(const f32x4*)(qA  + i * 4);
    f32x4 b0 = *(const f32x4*)(k0A + 128 + i * 4);
    f32x4 b1 = *(const f32x4*)(k1A + 128 + i * 4);
    f32x4 qb = *(const f32x4*)(qA  + 128 + i * 4);
    f32x4 t;
#define HS(acc, u, w) t = (u) * (w); acc += (t[0] + t[1]) + (t[2] + t[3]);
    HS(d0, a1, a0) HS(d1, qa, a0) HS(d2, qa, a1)
    HS(d3, b1, b0) HS(d4, qb, b0) HS(d5, qb, b1)
    HS(d6, b0, a0) HS(d7, b0, a1) HS(d8, b1, a0) HS(d9, b1, a1)
    HS(d10, qb, a0) HS(d11, qb, a1)
#undef HS
  }
#define RED(dd) dd += dpp_xor1(dd); dd += dpp_xor2(dd); dd += dpp_hmirror(dd);
  RED(d0) RED(d1) RED(d2) RED(d3) RED(d4) RED(d5)
  RED(d6) RED(d7) RED(d8) RED(d9) RED(d10) RED(d11)
#undef RED
  if (e == 0) {
    float* dst = dots_s + (size_t)bh * 12 * 256 + p;
    dst[0*256]=d0; dst[1*256]=d1; dst[2*256]=d2;  dst[3*256]=d3;
    dst[4*256]=d4; dst[5*256]=d5; dst[6*256]=d6;  dst[7*256]=d7;
    dst[8*256]=d8; dst[9*256]=d9; dst[10*256]=d10; dst[11*256]=d11;
  }
}

// ---------------- scan: 2-step blocked (mini-WY) — ONE dep-round per 2 steps -----
#define R4(X) X(0) X(1) X(2) X(3)
#define CH 12                        // padded chunk stride (8 data + 4)
#define TSTEP 8
#define STEPF (3 * 16 * CH)          // 576 floats per step
#define TILEF (TSTEP * STEPF)        // 4608 floats per buffer

__global__ __launch_bounds__(64, 1) void scan_kernel(const float* __restrict__ q_s,
                                                     const float* __restrict__ k_s,
                                                     const float* __restrict__ v_s,
                                                     const float* __restrict__ beta_s,
                                                     const float* __restrict__ ge_s,
                                                     const float* __restrict__ dots_s,
                                                     float* __restrict__ o_s,
                                                     float* __restrict__ state_out) {
  const int blk = blockIdx.x;      // 0..511
  const int bh  = blk >> 5;        // chain 0..15
  const int wg  = blk & 31;        // v-group 0..31 (4 cols)
  const int lane = threadIdx.x;    // 0..63
  const int kr = lane & 15;        // k-sixteenth 0..15
  const int vi = lane >> 4;        // 0..3
  const int v  = wg * 4 + vi;      // global v column

  __shared__ __align__(16) float lds[2][TILEF];
  __shared__ __align__(16) float vbuf[2][2][TSTEP][4];
  __shared__ __align__(16) float lds_sc[256][20];  // packed per-pair scalars

  f32x4 s0 = {0.f, 0.f, 0.f, 0.f}, s1 = {0.f, 0.f, 0.f, 0.f};
#define DECLG(j) f32x4 Gk0_##j, Gk1_##j, Gq_##j;
  R4(DECLG)
#undef DECLG
  float Gv;
#define DECLSET(S) f32x4 S##_a0A,S##_a1A,S##_b0A,S##_b1A,S##_c0A,S##_c1A, \
                         S##_a0B,S##_a1B,S##_b0B,S##_b1B,S##_c0B,S##_c1B; \
  float S##_gA,S##_gB,S##_bb0A,S##_bb1A,S##_bb0B,S##_bb1B, \
        S##_d01A,S##_dq0A,S##_dq1A,S##_d01B,S##_dq0B,S##_dq1B, \
        S##_c00,S##_c01,S##_c10,S##_c11,S##_cq0,S##_cq1, \
        S##_mv0A,S##_mv1A,S##_mv0B,S##_mv1B;
  DECLSET(A) DECLSET(B)
#undef DECLSET

  const float* g_k0 = k_s + ((size_t)bh * 2 + 0) * 512 * 128;
  const float* g_k1 = k_s + ((size_t)bh * 2 + 1) * 512 * 128;
  const float* g_q  = q_s + (size_t)bh * 512 * 128;
  const float* g_v0w = v_s + ((size_t)bh * 2 + 0) * 512 * 128 + wg * 4;
  const float* g_v1w = v_s + ((size_t)bh * 2 + 1) * 512 * 128 + wg * 4;
  const float* b0p = beta_s + ((size_t)bh * 2 + 0) * 512;
  const float* b1p = beta_s + ((size_t)bh * 2 + 1) * 512;
  const float* gp  = ge_s + (size_t)bh * 512;
  const float* dp  = dots_s + (size_t)bh * 12 * 256;

  // pack per-pair scalars: {gA,gB,b0A,b1A, b0B,b1B,d01A,dq0A, dq1A,d01B,dq0B,dq1B,
  //                         c00,c01,c10,c11, cq0,cq1,pad,pad}
#pragma unroll
  for (int i = 0; i < 4; ++i) {
    int p = lane + i * 64;
    int tA = 2 * p;
    lds_sc[p][0] = gp[tA];      lds_sc[p][1] = gp[tA + 1];
    lds_sc[p][2] = b0p[tA];     lds_sc[p][3] = b1p[tA];
    lds_sc[p][4] = b0p[tA + 1]; lds_sc[p][5] = b1p[tA + 1];
#pragma unroll
    for (int j = 0; j < 12; ++j) lds_sc[p][6 + j] = dp[j * 256 + p];
  }

  const int vhalf = lane >> 5;
  const int vli = lane & 31;
  const int vtl = vli >> 2, vc = vli & 3;
  const float* vsrc = vhalf ? g_v1w : g_v0w;

#define LD1(j) { Gk0_##j = p0[lane + j * 64]; Gk1_##j = p1[lane + j * 64]; Gq_##j = pq[lane + j * 64]; }
#define LOAD_G(T) { const f32x4* __restrict__ p0 = (const f32x4*)(g_k0 + (size_t)(T) * 1024); \
                    const f32x4* __restrict__ p1 = (const f32x4*)(g_k1 + (size_t)(T) * 1024); \
                    const f32x4* __restrict__ pq = (const f32x4*)(g_q  + (size_t)(T) * 1024); \
                    R4(LD1) }
#define LOAD_V(T) { Gv = vsrc[(size_t)(T) * 1024 + vtl * 128 + vc]; }
#define WR1(j) { int g_ = lane + 64 * j; int tl_ = g_ >> 5; int kr_ = (g_ & 31) >> 1; \
                 int c_ = 4 * (g_ & 1); \
    *(f32x4*)&lds[bsel][((tl_ * 3 + 0) * 16 + kr_) * CH + c_] = Gk0_##j; \
    *(f32x4*)&lds[bsel][((tl_ * 3 + 1) * 16 + kr_) * CH + c_] = Gk1_##j; \
    *(f32x4*)&lds[bsel][((tl_ * 3 + 2) * 16 + kr_) * CH + c_] = Gq_##j; }
#define WRITE_G(b) { const int bsel = (b); R4(WR1) }
#define WRITE_V(b) { vbuf[b][vhalf][vtl][vc] = Gv; }

#define LOAD_PAIR(S, bufx, tlx, pg) { \
    const f32x4* pk0A_ = (const f32x4*)&lds[bufx][(((tlx) * 3 + 0) * 16 + kr) * CH]; \
    const f32x4* pk1A_ = (const f32x4*)&lds[bufx][(((tlx) * 3 + 1) * 16 + kr) * CH]; \
    const f32x4* pqA_  = (const f32x4*)&lds[bufx][(((tlx) * 3 + 2) * 16 + kr) * CH]; \
    const f32x4* pk0B_ = (const f32x4*)&lds[bufx][((((tlx) + 1) * 3 + 0) * 16 + kr) * CH]; \
    const f32x4* pk1B_ = (const f32x4*)&lds[bufx][((((tlx) + 1) * 3 + 1) * 16 + kr) * CH]; \
    const f32x4* pqB_  = (const f32x4*)&lds[bufx][((((tlx) + 1) * 3 + 2) * 16 + kr) * CH]; \
    S##_a0A = pk0A_[0]; S##_a1A = pk0A_[1]; \
    S##_b0A = pk1A_[0]; S##_b1A = pk1A_[1]; \
    S##_c0A = pqA_[0];  S##_c1A = pqA_[1]; \
    S##_a0B = pk0B_[0]; S##_a1B = pk0B_[1]; \
    S##_b0B = pk1B_[0]; S##_b1B = pk1B_[1]; \
    S##_c0B = pqB_[0];  S##_c1B = pqB_[1]; \
    const f32x4* sc_ = (const f32x4*)&lds_sc[(pg) & 255][0]; \
    f32x4 y0_ = sc_[0], y1_ = sc_[1], y2_ = sc_[2], y3_ = sc_[3], y4_ = sc_[4]; \
    S##_gA = y0_[0]; S##_gB = y0_[1]; S##_bb0A = y0_[2]; S##_bb1A = y0_[3]; \
    S##_bb0B = y1_[0]; S##_bb1B = y1_[1]; S##_d01A = y1_[2]; S##_dq0A = y1_[3]; \
    S##_dq1A = y2_[0]; S##_d01B = y2_[1]; S##_dq0B = y2_[2]; S##_dq1B = y2_[3]; \
    S##_c00 = y3_[0]; S##_c01 = y3_[1]; S##_c10 = y3_[2]; S##_c11 = y3_[3]; \
    S##_cq0 = y4_[0]; S##_cq1 = y4_[1]; \
    S##_mv0A = vbuf[bufx][0][tlx][vi]; S##_mv1A = vbuf[bufx][1][tlx][vi]; \
    S##_mv0B = vbuf[bufx][0][(tlx) + 1][vi]; S##_mv1B = vbuf[bufx][1][(tlx) + 1][vi]; } \
    __builtin_amdgcn_sched_barrier(0);

#define COMPUTE_PAIR(S, pg) { \
    f32x4 r0A_ = S##_a0A * s0; r0A_ += S##_a1A * s1; \
    f32x4 r1A_ = S##_b0A * s0; r1A_ += S##_b1A * s1; \
    f32x4 rqA_ = S##_c0A * s0; rqA_ += S##_c1A * s1; \
    f32x4 r0B_ = S##_a0B * s0; r0B_ += S##_a1B * s1; \
    f32x4 r1B_ = S##_b0B * s0; r1B_ += S##_b1B * s1; \
    f32x4 rqB_ = S##_c0B * s0; rqB_ += S##_c1B * s1; \
    float h0A = (r0A_[0] + r0A_[1]) + (r0A_[2] + r0A_[3]); \
    float h1A = (r1A_[0] + r1A_[1]) + (r1A_[2] + r1A_[3]); \
    float hqA = (rqA_[0] + rqA_[1]) + (rqA_[2] + rqA_[3]); \
    float h0B = (r0B_[0] + r0B_[1]) + (r0B_[2] + r0B_[3]); \
    float h1B = (r1B_[0] + r1B_[1]) + (r1B_[2] + r1B_[3]); \
    float hqB = (rqB_[0] + rqB_[1]) + (rqB_[2] + rqB_[3]); \
    h0A += dpp_xor1(h0A); h1A += dpp_xor1(h1A); hqA += dpp_xor1(hqA); \
    h0B += dpp_xor1(h0B); h1B += dpp_xor1(h1B); hqB += dpp_xor1(hqB); \
    h0A += dpp_xor2(h0A); h1A += dpp_xor2(h1A); hqA += dpp_xor2(hqA); \
    h0B += dpp_xor2(h0B); h1B += dpp_xor2(h1B); hqB += dpp_xor2(hqB); \
    h0A += dpp_hmirror(h0A); h1A += dpp_hmirror(h1A); hqA += dpp_hmirror(hqA); \
    h0B += dpp_hmirror(h0B); h1B += dpp_hmirror(h1B); hqB += dpp_hmirror(hqB); \
    h0A += dpp_rmirror(h0A); h1A += dpp_rmirror(h1A); hqA += dpp_rmirror(hqA); \
    h0B += dpp_rmirror(h0B); h1B += dpp_rmirror(h1B); hqB += dpp_rmirror(hqB); \
    const float u0A_ = (S##_mv0A - S##_gA * h0A) * S##_bb0A; \
    const float u1A_ = (S##_mv1A - S##_gA * h1A - S##_d01A * u0A_) * S##_bb1A; \
    const float u0B_ = (S##_mv0B - S##_gB * (S##_gA * h0B + S##_c00 * u0A_ + S##_c01 * u1A_)) * S##_bb0B; \
    const float u1B_ = (S##_mv1B - S##_gB * (S##_gA * h1B + S##_c10 * u0A_ + S##_c11 * u1A_) \
                        - S##_d01B * u0B_) * S##_bb1B; \
    const float oA_ = S##_gA * hqA + S##_dq0A * u0A_ + S##_dq1A * u1A_; \
    const float oB_ = S##_gB * (S##_gA * hqB + S##_cq0 * u0A_ + S##_cq1 * u1A_) \
                      + S##_dq0B * u0B_ + S##_dq1B * u1B_; \
    const float gg_ = S##_gA * S##_gB; \
    const float w0_ = S##_gB * u0A_, w1_ = S##_gB * u1A_; \
    s0 *= gg_; s0 += S##_a0A * w0_; s0 += S##_b0A * w1_; s0 += S##_a0B * u0B_; s0 += S##_b0B * u1B_; \
    s1 *= gg_; s1 += S##_a1A * w0_; s1 += S##_b1A * w1_; s1 += S##_a1B * u0B_; s1 += S##_b1B * u1B_; \
    if (kr == 0) { const int tA_ = 2 * (pg); \
      o_s[((size_t)bh * 512 + tA_) * 128 + v] = oA_; \
      o_s[((size_t)bh * 512 + tA_ + 1) * 128 + v] = oB_; } }

  LOAD_G(0) LOAD_V(0)
  WRITE_G(0) WRITE_V(0)
  LOAD_G(1) LOAD_V(1)
  LOAD_PAIR(A, 0, 0, 0)

  for (int T = 0; T < 64; ++T) {
    const int buf = T & 1;
    if (T < 63) { WRITE_G(buf ^ 1) WRITE_V(buf ^ 1) }
    if (T < 62) { LOAD_G(T + 2) LOAD_V(T + 2) }
    const int p0i = T * 4;
    LOAD_PAIR(B, buf, 2, p0i + 1)              COMPUTE_PAIR(A, p0i + 0)
    LOAD_PAIR(A, buf, 4, p0i + 2)              COMPUTE_PAIR(B, p0i + 1)
    LOAD_PAIR(B, buf, 6, p0i + 3)              COMPUTE_PAIR(A, p0i + 2)
    LOAD_PAIR(A, buf ^ 1, 0, (p0i + 4) & 255)  COMPUTE_PAIR(B, p0i + 3)
  }

  float* base = state_out + (size_t)bh * 128 * 128 + v;
#pragma unroll
  for (int i = 0; i < 4; ++i) {
    base[(kr * 8 + i) * 128]     = s0[i];
    base[(kr * 8 + 4 + i) * 128] = s1[i];
  }
}

// ---------------- rmsnorm + gate silu -> bf16 A for final GEMM ----------------
__global__ __launch_bounds__(128) void post_kernel(const float* __restrict__ o_s,
                                                   const float* __restrict__ qkvg,
                                                   const float* __restrict__ norm_w,
                                                   __hip_bfloat16* __restrict__ Afin) {
  int bt = blockIdx.x;
  int h = blockIdx.y;
  int d = threadIdx.x;
  int b = bt >> 9, t = bt & 511;
  int bh = b * 8 + h;
  float o = o_s[((size_t)bh * 512 + t) * 128 + d];
  __shared__ float red[2];
  float ss = o * o;
#pragma unroll
  for (int off = 32; off; off >>= 1) ss += __shfl_down(ss, off);
  if ((d & 63) == 0) red[d >> 6] = ss;
  __syncthreads();
  float mean = (red[0] + red[1]) * (1.f / 128.f);
  float r = rsqrtf(mean + 1e-5f);
  float gate = qkvg[(size_t)bt * NFUSE + 5120 + h * 128 + d];
  float val = o * r * norm_w[d] * silu_f(gate);
  Afin[(size_t)bt * 1024 + h * 128 + d] = __float2bfloat16(val);
}

extern "C" void kernel_launch(void* const* d_in, const int* in_sizes, int n_in,
                              void* d_out, int out_size, void* d_ws, size_t ws_size,
                              hipStream_t stream) {
  const float* x       = (const float*)d_in[0];
  const float* Wq      = (const float*)d_in[1];
  const float* Wk      = (const float*)d_in[2];
  const float* Wv      = (const float*)d_in[3];
  const float* Wb      = (const float*)d_in[4];
  const float* Wa      = (const float*)d_in[5];
  const float* A_log   = (const float*)d_in[6];
  const float* dt_bias = (const float*)d_in[7];
  const float* cqw     = (const float*)d_in[8];
  const float* ckw     = (const float*)d_in[9];
  const float* cvw     = (const float*)d_in[10];
  const float* Wg      = (const float*)d_in[11];
  const float* norm_w  = (const float*)d_in[12];
  const float* Wo      = (const float*)d_in[13];

  char* ws = (char*)d_ws;
  size_t off = 0;
  auto alloc = [&](size_t bytes) {
    void* p = ws + off;
    off += (bytes + 255) & ~(size_t)255;
    return p;
  };
  __hip_bfloat16* xbf  = (__hip_bfloat16*)alloc((size_t)2097152 * 2);
  __hip_bfloat16* WT   = (__hip_bfloat16*)alloc((size_t)NFUSE * 2048 * 2);  // fused q|k|v|g, [N][K]
  __hip_bfloat16* WoT  = (__hip_bfloat16*)alloc((size_t)2097152 * 2);
  float* qkvg   = (float*)alloc((size_t)ROWS * NFUSE * 4);
  float* q_s    = (float*)alloc((size_t)1048576 * 4);
  float* k_s    = (float*)alloc((size_t)2097152 * 4);
  float* v_s    = (float*)alloc((size_t)2097152 * 4);
  float* beta_s = (float*)alloc((size_t)16384 * 4);
  float* ge_s   = (float*)alloc((size_t)8192 * 4);
  float* dots_s = (float*)alloc((size_t)16 * 12 * 256 * 4);
  float* o_s    = (float*)alloc((size_t)1048576 * 4);
  __hip_bfloat16* Afin = (__hip_bfloat16*)alloc((size_t)1048576 * 2);

  float* out_main  = (float*)d_out;
  float* out_state = out_main + 2097152;

  dim3 tb(32, 8);
  f2bf_kernel<<<8192, 256, 0, stream>>>(x, xbf, 2097152);
  transpose5_kernel<<<dim3(64, 64, 5), tb, 0, stream>>>(Wq, Wk, Wv, Wg, Wo, WT, WoT);

  gemm_bf16_64<<<dim3(48, 16), 256, 0, stream>>>(xbf, WT, qkvg, 1024, NFUSE, 2048);
  ba_fused_kernel<<<1024, 64, 0, stream>>>(x, Wb, Wa, A_log, dt_bias, beta_s, ge_s);

  conv_qkv_kernel<<<dim3(1024, 40), 128, 0, stream>>>(qkvg, cqw, ckw, cvw, q_s, k_s, v_s);
  dots_kernel<<<dim3(16, 32), 64, 0, stream>>>(q_s, k_s, dots_s);

  scan_kernel<<<512, 64, 0, stream>>>(q_s, k_s, v_s, beta_s, ge_s, dots_s, o_s, out_state);

  post_kernel<<<dim3(1024, 8), 128, 0, stream>>>(o_s, qkvg, norm_w, Afin);
  gemm_bf16_64<<<dim3(16, 16), 256, 0, stream>>>(Afin, WoT, out_main, 1024, 2048, 1024);
}

// Round 16
// 236.326 us; speedup vs baseline: 1.5929x; 1.0217x over previous
//
#include <hip/hip_runtime.h>
#include <hip/hip_bf16.h>
#include <cmath>

#define B_   2
#define L_   512
#define HID  2048
#define DH   128
#define NH   8
#define NHH  2
#define ROWS 1024  // B_*L_
#define NFUSE 6144 // 1024(q)+2048(k)+2048(v)+1024(g)

typedef float  f32x2  __attribute__((ext_vector_type(2)));
typedef float  f32x4  __attribute__((ext_vector_type(4)));
typedef __bf16 bf16x8 __attribute__((ext_vector_type(8)));

#define AS1(p) ((const __attribute__((address_space(1))) unsigned int*)(p))
#define AS3(p) ((__attribute__((address_space(3))) unsigned int*)(p))

__device__ __forceinline__ float dpp_xor1(float x) {
  int r = __builtin_amdgcn_update_dpp(0, __float_as_int(x), 0xB1, 0xF, 0xF, true);
  return __int_as_float(r);
}
__device__ __forceinline__ float dpp_xor2(float x) {
  int r = __builtin_amdgcn_update_dpp(0, __float_as_int(x), 0x4E, 0xF, 0xF, true);
  return __int_as_float(r);
}
__device__ __forceinline__ float dpp_hmirror(float x) {  // mirror within 8
  int r = __builtin_amdgcn_update_dpp(0, __float_as_int(x), 0x141, 0xF, 0xF, true);
  return __int_as_float(r);
}
__device__ __forceinline__ float dpp_rmirror(float x) {  // mirror within 16
  int r = __builtin_amdgcn_update_dpp(0, __float_as_int(x), 0x140, 0xF, 0xF, true);
  return __int_as_float(r);
}

// ---- packed-FP32 VOP3P helpers. NOTE (round-15 lesson): v_pk_*_f32 sources
// must be 64-bit VGPR PAIRS — no single-VGPR broadcast via op_sel_hi (that's
// packed-16-bit only). Scalar broadcast = build {s,s} pair first.
__device__ __forceinline__ f32x2 pk_mul(f32x2 a, f32x2 b) {
  f32x2 d; asm("v_pk_mul_f32 %0, %1, %2" : "=v"(d) : "v"(a), "v"(b)); return d;
}
__device__ __forceinline__ f32x2 pk_fma(f32x2 a, f32x2 b, f32x2 c) {
  f32x2 d; asm("v_pk_fma_f32 %0, %1, %2, %3" : "=v"(d) : "v"(a), "v"(b), "v"(c)); return d;
}
__device__ __forceinline__ f32x2 bc2(float s) { f32x2 r; r[0] = s; r[1] = s; return r; }
__device__ __forceinline__ f32x2 lo2(f32x4 x) { f32x2 r; r[0] = x[0]; r[1] = x[1]; return r; }
__device__ __forceinline__ f32x2 hi2(f32x4 x) { f32x2 r; r[0] = x[2]; r[1] = x[3]; return r; }

// ---------------- f32 -> bf16 elementwise ----------------
__global__ void f2bf_kernel(const float* __restrict__ in, __hip_bfloat16* __restrict__ out, int n) {
  int i = blockIdx.x * 256 + threadIdx.x;
  if (i < n) out[i] = __float2bfloat16(in[i]);
}

// ---------------- 5 weight transposes in one dispatch (blockIdx.z selects) -------
__global__ __launch_bounds__(256) void transpose5_kernel(const float* __restrict__ Wq,
                                                         const float* __restrict__ Wk,
                                                         const float* __restrict__ Wv,
                                                         const float* __restrict__ Wg,
                                                         const float* __restrict__ Wo,
                                                         __hip_bfloat16* __restrict__ WT,
                                                         __hip_bfloat16* __restrict__ WoT) {
  const float* in; __hip_bfloat16* out; int K, N;
  switch (blockIdx.z) {
    case 0: in = Wq; out = WT;                          K = 2048; N = 1024; break;
    case 1: in = Wk; out = WT + (size_t)1024 * 2048;    K = 2048; N = 2048; break;
    case 2: in = Wv; out = WT + (size_t)3072 * 2048;    K = 2048; N = 2048; break;
    case 3: in = Wg; out = WT + (size_t)5120 * 2048;    K = 2048; N = 1024; break;
    default: in = Wo; out = WoT;                        K = 1024; N = 2048; break;
  }
  __shared__ float tile[32][33];
  int n0 = blockIdx.x * 32, k0 = blockIdx.y * 32;
  if (n0 >= N || k0 >= K) return;
  int tx = threadIdx.x, ty = threadIdx.y;  // 32 x 8
#pragma unroll
  for (int i = 0; i < 32; i += 8)
    tile[ty + i][tx] = in[(size_t)(k0 + ty + i) * N + n0 + tx];
  __syncthreads();
#pragma unroll
  for (int i = 0; i < 32; i += 8)
    out[(size_t)(n0 + ty + i) * K + k0 + tx] = __float2bfloat16(tile[tx][ty + i]);
}

// ---------------- bf16 MFMA GEMM, 64x128 tile ----------------
__global__ __launch_bounds__(256) void gemm_bf16_64(const __hip_bfloat16* __restrict__ A,
                                                    const __hip_bfloat16* __restrict__ BT,
                                                    float* __restrict__ C, int M, int N, int K) {
  __shared__ __align__(16) __hip_bfloat16 lA[64 * 32];
  __shared__ __align__(16) __hip_bfloat16 lB[128 * 32];
  const int tid = threadIdx.x;
  const int lane = tid & 63;
  const int w = tid >> 6;
  const int row0 = blockIdx.y * 64;
  const int col0 = blockIdx.x * 128;
  f32x4 acc[4][2];
#pragma unroll
  for (int m = 0; m < 4; ++m)
#pragma unroll
    for (int n = 0; n < 2; ++n) acc[m][n] = {0.f, 0.f, 0.f, 0.f};
  const int fr = lane & 15;
  const int ko = (lane >> 4) * 8;
  for (int kt = 0; kt < K; kt += 32) {
    {
      int elem = (w * 64 + lane) * 8;
      int rr = elem >> 5, cc = elem & 31;
      const __hip_bfloat16* srcA = A + (size_t)(row0 + rr) * K + kt + cc;
      __builtin_amdgcn_global_load_lds(AS1(srcA), AS3(&lA[w * 512]), 16, 0, 0);
    }
#pragma unroll
    for (int i = 0; i < 2; ++i) {
      int elem = ((i * 4 + w) * 64 + lane) * 8;
      int rr = elem >> 5, cc = elem & 31;
      const __hip_bfloat16* srcB = BT + (size_t)(col0 + rr) * K + kt + cc;
      __builtin_amdgcn_global_load_lds(AS1(srcB), AS3(&lB[(i * 4 + w) * 512]), 16, 0, 0);
    }
    __syncthreads();
    bf16x8 af[4], bfr[2];
#pragma unroll
    for (int m = 0; m < 4; ++m)
      af[m] = *reinterpret_cast<const bf16x8*>(&lA[(m * 16 + fr) * 32 + ko]);
#pragma unroll
    for (int n = 0; n < 2; ++n)
      bfr[n] = *reinterpret_cast<const bf16x8*>(&lB[(w * 32 + n * 16 + fr) * 32 + ko]);
#pragma unroll
    for (int m = 0; m < 4; ++m)
#pragma unroll
      for (int n = 0; n < 2; ++n)
        acc[m][n] = __builtin_amdgcn_mfma_f32_16x16x32_bf16(af[m], bfr[n], acc[m][n], 0, 0, 0);
    __syncthreads();
  }
  const int rq = (lane >> 4) * 4;
#pragma unroll
  for (int m = 0; m < 4; ++m)
#pragma unroll
    for (int n = 0; n < 2; ++n)
#pragma unroll
      for (int r = 0; r < 4; ++r)
        C[(size_t)(row0 + m * 16 + rq + r) * N + (col0 + w * 32 + n * 16 + fr)] =
            acc[m][n][r];
}

__device__ __forceinline__ float silu_f(float y) { return y / (1.f + __expf(-y)); }

// ---------------- fused x@Wb / x@Wa + beta/g transforms (one block per row) ------
__global__ __launch_bounds__(64) void ba_fused_kernel(const float* __restrict__ x,
                                                      const float* __restrict__ Wb,
                                                      const float* __restrict__ Wa,
                                                      const float* __restrict__ A_log,
                                                      const float* __restrict__ dt_bias,
                                                      float* __restrict__ beta_s,
                                                      float* __restrict__ ge_s) {
  const int row = blockIdx.x;   // b*512 + t
  const int lane = threadIdx.x;
  f32x4 aB0 = {0,0,0,0}, aB1 = {0,0,0,0}, aB2 = {0,0,0,0}, aB3 = {0,0,0,0};
  f32x4 aA0 = {0,0,0,0}, aA1 = {0,0,0,0};
  const float* xr = x + (size_t)row * HID;
  for (int i = 0; i < 32; ++i) {
    int k = lane + i * 64;
    float xv = xr[k];
    const f32x4* wb4 = (const f32x4*)(Wb + (size_t)k * 16);
    const f32x4* wa4 = (const f32x4*)(Wa + (size_t)k * 8);
    aB0 += wb4[0] * xv; aB1 += wb4[1] * xv; aB2 += wb4[2] * xv; aB3 += wb4[3] * xv;
    aA0 += wa4[0] * xv; aA1 += wa4[1] * xv;
  }
  __shared__ float red[64][25];
#pragma unroll
  for (int c = 0; c < 4; ++c) {
    red[lane][0 + c]  = aB0[c];
    red[lane][4 + c]  = aB1[c];
    red[lane][8 + c]  = aB2[c];
    red[lane][12 + c] = aB3[c];
    red[lane][16 + c] = aA0[c];
    red[lane][20 + c] = aA1[c];
  }
  // single wave: in-order LDS, no barrier needed
  if (lane < 24) {
    float s = 0.f;
#pragma unroll 8
    for (int i = 0; i < 64; ++i) s += red[i][lane];
    int b = row >> 9, t = row & 511;
    if (lane < 16) {
      int j = lane >> 3, h = lane & 7;
      beta_s[(((size_t)(b * 8 + h)) * 2 + j) * 512 + t] = 2.f / (1.f + __expf(-s));
    } else {
      int h = lane - 16;
      float vv = s + dt_bias[h];
      float sp = (vv > 20.f) ? vv : log1pf(__expf(vv));
      ge_s[((size_t)(b * 8 + h)) * 512 + t] = __expf(-__expf(A_log[h]) * sp);
    }
  }
}

// ---------------- fused conv + silu (+l2norm for q/k) for q,k,v ----------------
__global__ __launch_bounds__(128) void conv_qkv_kernel(const float* __restrict__ qkvg,
                                                       const float* __restrict__ wq,
                                                       const float* __restrict__ wk,
                                                       const float* __restrict__ wv,
                                                       float* __restrict__ q_s,
                                                       float* __restrict__ k_s,
                                                       float* __restrict__ v_s) {
  int bt = blockIdx.x;
  int yy = blockIdx.y;
  int d  = threadIdx.x;
  int b = bt >> 9, t = bt & 511;
  __shared__ float red[2];
  if (yy < 8) {
    int h = yy, c = h * 128 + d;
    float y = 0.f;
#pragma unroll
    for (int tau = 0; tau < 4; ++tau) {
      int tt = t - 3 + tau;
      float xv = (tt >= 0) ? qkvg[(size_t)(b * 512 + tt) * NFUSE + c] : 0.f;
      y += xv * wq[c * 4 + tau];
    }
    y = silu_f(y);
    float ss = y * y;
#pragma unroll
    for (int off = 32; off; off >>= 1) ss += __shfl_down(ss, off);
    if ((d & 63) == 0) red[d >> 6] = ss;
    __syncthreads();
    float scale = (1.f / fmaxf(sqrtf(red[0] + red[1]), 1e-12f)) * 0.08838834764831845f;
    q_s[((size_t)(b * 8 + h) * 512 + t) * 128 + d] = y * scale;
  } else if (yy < 24) {
    int jh = yy - 8;
    int j = jh >> 3, h = jh & 7;
    int c = j * 1024 + h * 128 + d;
    float y = 0.f;
#pragma unroll
    for (int tau = 0; tau < 4; ++tau) {
      int tt = t - 3 + tau;
      float xv = (tt >= 0) ? qkvg[(size_t)(b * 512 + tt) * NFUSE + 1024 + c] : 0.f;
      y += xv * wk[c * 4 + tau];
    }
    y = silu_f(y);
    float ss = y * y;
#pragma unroll
    for (int off = 32; off; off >>= 1) ss += __shfl_down(ss, off);
    if ((d & 63) == 0) red[d >> 6] = ss;
    __syncthreads();
    float scale = 1.f / fmaxf(sqrtf(red[0] + red[1]), 1e-12f);
    k_s[(((size_t)(b * 8 + h) * 2 + j) * 512 + t) * 128 + d] = y * scale;
  } else {
    int jh = yy - 24;
    int j = jh >> 3, h = jh & 7;
    int c = j * 1024 + h * 128 + d;
    float y = 0.f;
#pragma unroll
    for (int tau = 0; tau < 4; ++tau) {
      int tt = t - 3 + tau;
      float xv = (tt >= 0) ? qkvg[(size_t)(b * 512 + tt) * NFUSE + 3072 + c] : 0.f;
      y += xv * wv[c * 4 + tau];
    }
    v_s[(((size_t)(b * 8 + h) * 2 + j) * 512 + t) * 128 + d] = silu_f(y);
  }
}

// ---------------- pair cross-dots (input-only), 12 scalars per pair p=t/2 -------
__global__ __launch_bounds__(64) void dots_kernel(const float* __restrict__ q_s,
                                                  const float* __restrict__ k_s,
                                                  float* __restrict__ dots_s) {
  const int bh = blockIdx.x;     // 0..15
  const int py = blockIdx.y;     // 0..31
  const int lane = threadIdx.x;
  const int e  = lane & 7;       // 16-float slice
  const int pl = lane >> 3;      // pair-in-block 0..7
  const int p = py * 8 + pl;     // pair 0..255
  const int tA = 2 * p;
  const float* k0A = k_s + ((size_t)bh * 2 + 0) * 512 * 128 + (size_t)tA * 128 + e * 16;
  const float* k1A = k_s + ((size_t)bh * 2 + 1) * 512 * 128 + (size_t)tA * 128 + e * 16;
  const float* qA  = q_s + (size_t)bh * 512 * 128 + (size_t)tA * 128 + e * 16;
  float d0=0,d1=0,d2=0,d3=0,d4=0,d5=0,d6=0,d7=0,d8=0,d9=0,d10=0,d11=0;
#pragma unroll
  for (int i = 0; i < 4; ++i) {
    f32x4 a0 = *(const f32x4*)(k0A + i * 4);
    f32x4 a1 = *(const f32x4*)(k1A + i * 4);
    f32x4 qa = *(const f32x4*)(qA  + i * 4);
    f32x4 b0 = *(const f32x4*)(k0A + 128 + i * 4);
    f32x4 b1 = *(const f32x4*)(k1A + 128 + i * 4);
    f32x4 qb = *(const f32x4*)(qA  + 128 + i * 4);
    f32x4 t;
#define HS(acc, u, w) t = (u) * (w); acc += (t[0] + t[1]) + (t[2] + t[3]);
    HS(d0, a1, a0) HS(d1, qa, a0) HS(d2, qa, a1)
    HS(d3, b1, b0) HS(d4, qb, b0) HS(d5, qb, b1)
    HS(d6, b0, a0) HS(d7, b0, a1) HS(d8, b1, a0) HS(d9, b1, a1)
    HS(d10, qb, a0) HS(d11, qb, a1)
#undef HS
  }
#define RED(dd) dd += dpp_xor1(dd); dd += dpp_xor2(dd); dd += dpp_hmirror(dd);
  RED(d0) RED(d1) RED(d2) RED(d3) RED(d4) RED(d5)
  RED(d6) RED(d7) RED(d8) RED(d9) RED(d10) RED(d11)
#undef RED
  if (e == 0) {
    float* dst = dots_s + (size_t)bh * 12 * 256 + p;
    dst[0*256]=d0; dst[1*256]=d1; dst[2*256]=d2;  dst[3*256]=d3;
    dst[4*256]=d4; dst[5*256]=d5; dst[6*256]=d6;  dst[7*256]=d7;
    dst[8*256]=d8; dst[9*256]=d9; dst[10*256]=d10; dst[11*256]=d11;
  }
}

// ---------------- scan: 2-step blocked + packed-FP32 math ----------------
// Verified 119µs structure; dot/update chains use v_pk_fma_f32 (pair operands
// only — scalar broadcasts materialized as {s,s} via bc2()).
#define R4(X) X(0) X(1) X(2) X(3)
#define CH 12                        // padded chunk stride (8 data + 4)
#define TSTEP 8
#define STEPF (3 * 16 * CH)          // 576 floats per step
#define TILEF (TSTEP * STEPF)        // 4608 floats per buffer

__global__ __launch_bounds__(64, 1) void scan_kernel(const float* __restrict__ q_s,
                                                     const float* __restrict__ k_s,
                                                     const float* __restrict__ v_s,
                                                     const float* __restrict__ beta_s,
                                                     const float* __restrict__ ge_s,
                                                     const float* __restrict__ dots_s,
                                                     float* __restrict__ o_s,
                                                     float* __restrict__ state_out) {
  const int blk = blockIdx.x;      // 0..511
  const int bh  = blk >> 5;        // chain 0..15
  const int wg  = blk & 31;        // v-group 0..31 (4 cols)
  const int lane = threadIdx.x;    // 0..63
  const int kr = lane & 15;        // k-sixteenth 0..15
  const int vi = lane >> 4;        // 0..3
  const int v  = wg * 4 + vi;      // global v column

  __shared__ __align__(16) float lds[2][TILEF];
  __shared__ __align__(16) float vbuf[2][2][TSTEP][4];
  __shared__ __align__(16) float lds_sc[256][20];  // packed per-pair scalars

  f32x2 s0l = {0.f, 0.f}, s0h = {0.f, 0.f}, s1l = {0.f, 0.f}, s1h = {0.f, 0.f};
#define DECLG(j) f32x4 Gk0_##j, Gk1_##j, Gq_##j;
  R4(DECLG)
#undef DECLG
  float Gv;
#define DECLSET(S) f32x2 S##_a0Al,S##_a0Ah,S##_a1Al,S##_a1Ah, \
                         S##_b0Al,S##_b0Ah,S##_b1Al,S##_b1Ah, \
                         S##_c0Al,S##_c0Ah,S##_c1Al,S##_c1Ah, \
                         S##_a0Bl,S##_a0Bh,S##_a1Bl,S##_a1Bh, \
                         S##_b0Bl,S##_b0Bh,S##_b1Bl,S##_b1Bh, \
                         S##_c0Bl,S##_c0Bh,S##_c1Bl,S##_c1Bh; \
  float S##_gA,S##_gB,S##_bb0A,S##_bb1A,S##_bb0B,S##_bb1B, \
        S##_d01A,S##_dq0A,S##_dq1A,S##_d01B,S##_dq0B,S##_dq1B, \
        S##_c00,S##_c01,S##_c10,S##_c11,S##_cq0,S##_cq1, \
        S##_mv0A,S##_mv1A,S##_mv0B,S##_mv1B;
  DECLSET(A) DECLSET(B)
#undef DECLSET

  const float* g_k0 = k_s + ((size_t)bh * 2 + 0) * 512 * 128;
  const float* g_k1 = k_s + ((size_t)bh * 2 + 1) * 512 * 128;
  const float* g_q  = q_s + (size_t)bh * 512 * 128;
  const float* g_v0w = v_s + ((size_t)bh * 2 + 0) * 512 * 128 + wg * 4;
  const float* g_v1w = v_s + ((size_t)bh * 2 + 1) * 512 * 128 + wg * 4;
  const float* b0p = beta_s + ((size_t)bh * 2 + 0) * 512;
  const float* b1p = beta_s + ((size_t)bh * 2 + 1) * 512;
  const float* gp  = ge_s + (size_t)bh * 512;
  const float* dp  = dots_s + (size_t)bh * 12 * 256;

#pragma unroll
  for (int i = 0; i < 4; ++i) {
    int p = lane + i * 64;
    int tA = 2 * p;
    lds_sc[p][0] = gp[tA];      lds_sc[p][1] = gp[tA + 1];
    lds_sc[p][2] = b0p[tA];     lds_sc[p][3] = b1p[tA];
    lds_sc[p][4] = b0p[tA + 1]; lds_sc[p][5] = b1p[tA + 1];
#pragma unroll
    for (int j = 0; j < 12; ++j) lds_sc[p][6 + j] = dp[j * 256 + p];
  }

  const int vhalf = lane >> 5;
  const int vli = lane & 31;
  const int vtl = vli >> 2, vc = vli & 3;
  const float* vsrc = vhalf ? g_v1w : g_v0w;

#define LD1(j) { Gk0_##j = p0[lane + j * 64]; Gk1_##j = p1[lane + j * 64]; Gq_##j = pq[lane + j * 64]; }
#define LOAD_G(T) { const f32x4* __restrict__ p0 = (const f32x4*)(g_k0 + (size_t)(T) * 1024); \
                    const f32x4* __restrict__ p1 = (const f32x4*)(g_k1 + (size_t)(T) * 1024); \
                    const f32x4* __restrict__ pq = (const f32x4*)(g_q  + (size_t)(T) * 1024); \
                    R4(LD1) }
#define LOAD_V(T) { Gv = vsrc[(size_t)(T) * 1024 + vtl * 128 + vc]; }
#define WR1(j) { int g_ = lane + 64 * j; int tl_ = g_ >> 5; int kr_ = (g_ & 31) >> 1; \
                 int c_ = 4 * (g_ & 1); \
    *(f32x4*)&lds[bsel][((tl_ * 3 + 0) * 16 + kr_) * CH + c_] = Gk0_##j; \
    *(f32x4*)&lds[bsel][((tl_ * 3 + 1) * 16 + kr_) * CH + c_] = Gk1_##j; \
    *(f32x4*)&lds[bsel][((tl_ * 3 + 2) * 16 + kr_) * CH + c_] = Gq_##j; }
#define WRITE_G(b) { const int bsel = (b); R4(WR1) }
#define WRITE_V(b) { vbuf[b][vhalf][vtl][vc] = Gv; }

#define LOAD_PAIR(S, bufx, tlx, pg) { \
    const f32x4* pk0A_ = (const f32x4*)&lds[bufx][(((tlx) * 3 + 0) * 16 + kr) * CH]; \
    const f32x4* pk1A_ = (const f32x4*)&lds[bufx][(((tlx) * 3 + 1) * 16 + kr) * CH]; \
    const f32x4* pqA_  = (const f32x4*)&lds[bufx][(((tlx) * 3 + 2) * 16 + kr) * CH]; \
    const f32x4* pk0B_ = (const f32x4*)&lds[bufx][((((tlx) + 1) * 3 + 0) * 16 + kr) * CH]; \
    const f32x4* pk1B_ = (const f32x4*)&lds[bufx][((((tlx) + 1) * 3 + 1) * 16 + kr) * CH]; \
    const f32x4* pqB_  = (const f32x4*)&lds[bufx][((((tlx) + 1) * 3 + 2) * 16 + kr) * CH]; \
    { f32x4 t_ = pk0A_[0]; S##_a0Al = lo2(t_); S##_a0Ah = hi2(t_); } \
    { f32x4 t_ = pk0A_[1]; S##_a1Al = lo2(t_); S##_a1Ah = hi2(t_); } \
    { f32x4 t_ = pk1A_[0]; S##_b0Al = lo2(t_); S##_b0Ah = hi2(t_); } \
    { f32x4 t_ = pk1A_[1]; S##_b1Al = lo2(t_); S##_b1Ah = hi2(t_); } \
    { f32x4 t_ = pqA_[0];  S##_c0Al = lo2(t_); S##_c0Ah = hi2(t_); } \
    { f32x4 t_ = pqA_[1];  S##_c1Al = lo2(t_); S##_c1Ah = hi2(t_); } \
    { f32x4 t_ = pk0B_[0]; S##_a0Bl = lo2(t_); S##_a0Bh = hi2(t_); } \
    { f32x4 t_ = pk0B_[1]; S##_a1Bl = lo2(t_); S##_a1Bh = hi2(t_); } \
    { f32x4 t_ = pk1B_[0]; S##_b0Bl = lo2(t_); S##_b0Bh = hi2(t_); } \
    { f32x4 t_ = pk1B_[1]; S##_b1Bl = lo2(t_); S##_b1Bh = hi2(t_); } \
    { f32x4 t_ = pqB_[0];  S##_c0Bl = lo2(t_); S##_c0Bh = hi2(t_); } \
    { f32x4 t_ = pqB_[1];  S##_c1Bl = lo2(t_); S##_c1Bh = hi2(t_); } \
    const f32x4* sc_ = (const f32x4*)&lds_sc[(pg) & 255][0]; \
    f32x4 y0_ = sc_[0], y1_ = sc_[1], y2_ = sc_[2], y3_ = sc_[3], y4_ = sc_[4]; \
    S##_gA = y0_[0]; S##_gB = y0_[1]; S##_bb0A = y0_[2]; S##_bb1A = y0_[3]; \
    S##_bb0B = y1_[0]; S##_bb1B = y1_[1]; S##_d01A = y1_[2]; S##_dq0A = y1_[3]; \
    S##_dq1A = y2_[0]; S##_d01B = y2_[1]; S##_dq0B = y2_[2]; S##_dq1B = y2_[3]; \
    S##_c00 = y3_[0]; S##_c01 = y3_[1]; S##_c10 = y3_[2]; S##_c11 = y3_[3]; \
    S##_cq0 = y4_[0]; S##_cq1 = y4_[1]; \
    S##_mv0A = vbuf[bufx][0][tlx][vi]; S##_mv1A = vbuf[bufx][1][tlx][vi]; \
    S##_mv0B = vbuf[bufx][0][(tlx) + 1][vi]; S##_mv1B = vbuf[bufx][1][(tlx) + 1][vi]; } \
    __builtin_amdgcn_sched_barrier(0);

#define COMPUTE_PAIR(S, pg) { \
    f32x2 acc0A = pk_mul(S##_a0Al, s0l); acc0A = pk_fma(S##_a0Ah, s0h, acc0A); \
    acc0A = pk_fma(S##_a1Al, s1l, acc0A); acc0A = pk_fma(S##_a1Ah, s1h, acc0A); \
    f32x2 acc1A = pk_mul(S##_b0Al, s0l); acc1A = pk_fma(S##_b0Ah, s0h, acc1A); \
    acc1A = pk_fma(S##_b1Al, s1l, acc1A); acc1A = pk_fma(S##_b1Ah, s1h, acc1A); \
    f32x2 accqA = pk_mul(S##_c0Al, s0l); accqA = pk_fma(S##_c0Ah, s0h, accqA); \
    accqA = pk_fma(S##_c1Al, s1l, accqA); accqA = pk_fma(S##_c1Ah, s1h, accqA); \
    f32x2 acc0B = pk_mul(S##_a0Bl, s0l); acc0B = pk_fma(S##_a0Bh, s0h, acc0B); \
    acc0B = pk_fma(S##_a1Bl, s1l, acc0B); acc0B = pk_fma(S##_a1Bh, s1h, acc0B); \
    f32x2 acc1B = pk_mul(S##_b0Bl, s0l); acc1B = pk_fma(S##_b0Bh, s0h, acc1B); \
    acc1B = pk_fma(S##_b1Bl, s1l, acc1B); acc1B = pk_fma(S##_b1Bh, s1h, acc1B); \
    f32x2 accqB = pk_mul(S##_c0Bl, s0l); accqB = pk_fma(S##_c0Bh, s0h, accqB); \
    accqB = pk_fma(S##_c1Bl, s1l, accqB); accqB = pk_fma(S##_c1Bh, s1h, accqB); \
    float h0A = acc0A[0] + acc0A[1]; \
    float h1A = acc1A[0] + acc1A[1]; \
    float hqA = accqA[0] + accqA[1]; \
    float h0B = acc0B[0] + acc0B[1]; \
    float h1B = acc1B[0] + acc1B[1]; \
    float hqB = accqB[0] + accqB[1]; \
    h0A += dpp_xor1(h0A); h1A += dpp_xor1(h1A); hqA += dpp_xor1(hqA); \
    h0B += dpp_xor1(h0B); h1B += dpp_xor1(h1B); hqB += dpp_xor1(hqB); \
    h0A += dpp_xor2(h0A); h1A += dpp_xor2(h1A); hqA += dpp_xor2(hqA); \
    h0B += dpp_xor2(h0B); h1B += dpp_xor2(h1B); hqB += dpp_xor2(hqB); \
    h0A += dpp_hmirror(h0A); h1A += dpp_hmirror(h1A); hqA += dpp_hmirror(hqA); \
    h0B += dpp_hmirror(h0B); h1B += dpp_hmirror(h1B); hqB += dpp_hmirror(hqB); \
    h0A += dpp_rmirror(h0A); h1A += dpp_rmirror(h1A); hqA += dpp_rmirror(hqA); \
    h0B += dpp_rmirror(h0B); h1B += dpp_rmirror(h1B); hqB += dpp_rmirror(hqB); \
    const float u0A_ = (S##_mv0A - S##_gA * h0A) * S##_bb0A; \
    const float u1A_ = (S##_mv1A - S##_gA * h1A - S##_d01A * u0A_) * S##_bb1A; \
    const float u0B_ = (S##_mv0B - S##_gB * (S##_gA * h0B + S##_c00 * u0A_ + S##_c01 * u1A_)) * S##_bb0B; \
    const float u1B_ = (S##_mv1B - S##_gB * (S##_gA * h1B + S##_c10 * u0A_ + S##_c11 * u1A_) \
                        - S##_d01B * u0B_) * S##_bb1B; \
    const float oA_ = S##_gA * hqA + S##_dq0A * u0A_ + S##_dq1A * u1A_; \
    const float oB_ = S##_gB * (S##_gA * hqB + S##_cq0 * u0A_ + S##_cq1 * u1A_) \
                      + S##_dq0B * u0B_ + S##_dq1B * u1B_; \
    const f32x2 ggp = bc2(S##_gA * S##_gB); \
    const f32x2 w0p = bc2(S##_gB * u0A_), w1p = bc2(S##_gB * u1A_); \
    const f32x2 u0Bp = bc2(u0B_), u1Bp = bc2(u1B_); \
    s0l = pk_mul(s0l, ggp); s0h = pk_mul(s0h, ggp); \
    s1l = pk_mul(s1l, ggp); s1h = pk_mul(s1h, ggp); \
    s0l = pk_fma(S##_a0Al, w0p, s0l); s0h = pk_fma(S##_a0Ah, w0p, s0h); \
    s1l = pk_fma(S##_a1Al, w0p, s1l); s1h = pk_fma(S##_a1Ah, w0p, s1h); \
    s0l = pk_fma(S##_b0Al, w1p, s0l); s0h = pk_fma(S##_b0Ah, w1p, s0h); \
    s1l = pk_fma(S##_b1Al, w1p, s1l); s1h = pk_fma(S##_b1Ah, w1p, s1h); \
    s0l = pk_fma(S##_a0Bl, u0Bp, s0l); s0h = pk_fma(S##_a0Bh, u0Bp, s0h); \
    s1l = pk_fma(S##_a1Bl, u0Bp, s1l); s1h = pk_fma(S##_a1Bh, u0Bp, s1h); \
    s0l = pk_fma(S##_b0Bl, u1Bp, s0l); s0h = pk_fma(S##_b0Bh, u1Bp, s0h); \
    s1l = pk_fma(S##_b1Bl, u1Bp, s1l); s1h = pk_fma(S##_b1Bh, u1Bp, s1h); \
    if (kr == 0) { const int tA_ = 2 * (pg); \
      o_s[((size_t)bh * 512 + tA_) * 128 + v] = oA_; \
      o_s[((size_t)bh * 512 + tA_ + 1) * 128 + v] = oB_; } }

  LOAD_G(0) LOAD_V(0)
  WRITE_G(0) WRITE_V(0)
  LOAD_G(1) LOAD_V(1)
  LOAD_PAIR(A, 0, 0, 0)

  for (int T = 0; T < 64; ++T) {
    const int buf = T & 1;
    if (T < 63) { WRITE_G(buf ^ 1) WRITE_V(buf ^ 1) }
    if (T < 62) { LOAD_G(T + 2) LOAD_V(T + 2) }
    const int p0i = T * 4;
    LOAD_PAIR(B, buf, 2, p0i + 1)              COMPUTE_PAIR(A, p0i + 0)
    LOAD_PAIR(A, buf, 4, p0i + 2)              COMPUTE_PAIR(B, p0i + 1)
    LOAD_PAIR(B, buf, 6, p0i + 3)              COMPUTE_PAIR(A, p0i + 2)
    LOAD_PAIR(A, buf ^ 1, 0, (p0i + 4) & 255)  COMPUTE_PAIR(B, p0i + 3)
  }

  float* base = state_out + (size_t)bh * 128 * 128 + v;
  base[(kr * 8 + 0) * 128] = s0l[0];
  base[(kr * 8 + 1) * 128] = s0l[1];
  base[(kr * 8 + 2) * 128] = s0h[0];
  base[(kr * 8 + 3) * 128] = s0h[1];
  base[(kr * 8 + 4) * 128] = s1l[0];
  base[(kr * 8 + 5) * 128] = s1l[1];
  base[(kr * 8 + 6) * 128] = s1h[0];
  base[(kr * 8 + 7) * 128] = s1h[1];
}

// ---------------- rmsnorm + gate silu -> bf16 A for final GEMM ----------------
__global__ __launch_bounds__(128) void post_kernel(const float* __restrict__ o_s,
                                                   const float* __restrict__ qkvg,
                                                   const float* __restrict__ norm_w,
                                                   __hip_bfloat16* __restrict__ Afin) {
  int bt = blockIdx.x;
  int h = blockIdx.y;
  int d = threadIdx.x;
  int b = bt >> 9, t = bt & 511;
  int bh = b * 8 + h;
  float o = o_s[((size_t)bh * 512 + t) * 128 + d];
  __shared__ float red[2];
  float ss = o * o;
#pragma unroll
  for (int off = 32; off; off >>= 1) ss += __shfl_down(ss, off);
  if ((d & 63) == 0) red[d >> 6] = ss;
  __syncthreads();
  float mean = (red[0] + red[1]) * (1.f / 128.f);
  float r = rsqrtf(mean + 1e-5f);
  float gate = qkvg[(size_t)bt * NFUSE + 5120 + h * 128 + d];
  float val = o * r * norm_w[d] * silu_f(gate);
  Afin[(size_t)bt * 1024 + h * 128 + d] = __float2bfloat16(val);
}

extern "C" void kernel_launch(void* const* d_in, const int* in_sizes, int n_in,
                              void* d_out, int out_size, void* d_ws, size_t ws_size,
                              hipStream_t stream) {
  const float* x       = (const float*)d_in[0];
  const float* Wq      = (const float*)d_in[1];
  const float* Wk      = (const float*)d_in[2];
  const float* Wv      = (const float*)d_in[3];
  const float* Wb      = (const float*)d_in[4];
  const float* Wa      = (const float*)d_in[5];
  const float* A_log   = (const float*)d_in[6];
  const float* dt_bias = (const float*)d_in[7];
  const float* cqw     = (const float*)d_in[8];
  const float* ckw     = (const float*)d_in[9];
  const float* cvw     = (const float*)d_in[10];
  const float* Wg      = (const float*)d_in[11];
  const float* norm_w  = (const float*)d_in[12];
  const float* Wo      = (const float*)d_in[13];

  char* ws = (char*)d_ws;
  size_t off = 0;
  auto alloc = [&](size_t bytes) {
    void* p = ws + off;
    off += (bytes + 255) & ~(size_t)255;
    return p;
  };
  __hip_bfloat16* xbf  = (__hip_bfloat16*)alloc((size_t)2097152 * 2);
  __hip_bfloat16* WT   = (__hip_bfloat16*)alloc((size_t)NFUSE * 2048 * 2);  // fused q|k|v|g, [N][K]
  __hip_bfloat16* WoT  = (__hip_bfloat16*)alloc((size_t)2097152 * 2);
  float* qkvg   = (float*)alloc((size_t)ROWS * NFUSE * 4);
  float* q_s    = (float*)alloc((size_t)1048576 * 4);
  float* k_s    = (float*)alloc((size_t)2097152 * 4);
  float* v_s    = (float*)alloc((size_t)2097152 * 4);
  float* beta_s = (float*)alloc((size_t)16384 * 4);
  float* ge_s   = (float*)alloc((size_t)8192 * 4);
  float* dots_s = (float*)alloc((size_t)16 * 12 * 256 * 4);
  float* o_s    = (float*)alloc((size_t)1048576 * 4);
  __hip_bfloat16* Afin = (__hip_bfloat16*)alloc((size_t)1048576 * 2);

  float* out_main  = (float*)d_out;
  float* out_state = out_main + 2097152;

  dim3 tb(32, 8);
  f2bf_kernel<<<8192, 256, 0, stream>>>(x, xbf, 2097152);
  transpose5_kernel<<<dim3(64, 64, 5), tb, 0, stream>>>(Wq, Wk, Wv, Wg, Wo, WT, WoT);

  gemm_bf16_64<<<dim3(48, 16), 256, 0, stream>>>(xbf, WT, qkvg, 1024, NFUSE, 2048);
  ba_fused_kernel<<<1024, 64, 0, stream>>>(x, Wb, Wa, A_log, dt_bias, beta_s, ge_s);

  conv_qkv_kernel<<<dim3(1024, 40), 128, 0, stream>>>(qkvg, cqw, ckw, cvw, q_s, k_s, v_s);
  dots_kernel<<<dim3(16, 32), 64, 0, stream>>>(q_s, k_s, dots_s);

  scan_kernel<<<512, 64, 0, stream>>>(q_s, k_s, v_s, beta_s, ge_s, dots_s, o_s, out_state);

  post_kernel<<<dim3(1024, 8), 128, 0, stream>>>(o_s, qkvg, norm_w, Afin);
  gemm_bf16_64<<<dim3(16, 16), 256, 0, stream>>>(Afin, WoT, out_main, 1024, 2048, 1024);
}